// Round 8
// baseline (711.191 us; speedup 1.0000x reference)
//
#include <hip/hip_runtime.h>
#include <math.h>

#define T 512
#define B 128
#define KK 8
#define HH 32
#define PP 32

// ws layout (floats)
#define WS_GX    0             /* gx [dir*B+b][t][96] = 12582912 floats */
#define WS_GS    6291456       /* alias gx dir=1 half: gumbel noise [t][b][8], written after GRU */
#define WS_HSEQ  12582912
#define WS_LOGITS 0            /* alias gx dir=0 half: scaled logits [t][b][64], written after GRU */
#define WS_INIT  16777216
#define WS_YSEQ  16778240

// d_out layout (floats)
#define OUT_A    0
#define OUT_B    16777216
#define OUT_C    25165824
#define OUT_Q    58720256
#define OUT_LQ   75497472
#define OUT_LP   75563008

#define TINV 2.0f
#define PSTAY 0.9f
#define OFFV (0.1f / 7.0f)
#define DPS (PSTAY - OFFV)
#define LOG_INV_K (-2.0794415416798357f)

typedef float f4v __attribute__((ext_vector_type(4)));
typedef __attribute__((address_space(3))) float as3f;

// async DMA global->LDS, 16B/lane, opaque to compiler (no auto waitcnt insertion)
__device__ __forceinline__ void dma16(unsigned ldsbyte, int voffbyte, const void* sbase) {
    asm volatile("s_mov_b32 m0, %0\n\t"
                 "global_load_lds_dwordx4 %1, %2"
                 :: "s"(ldsbyte), "v"(voffbyte), "s"(sbase)
                 : "memory");
}
// stores kept in asm: compiler does not track them -> no per-iter vmcnt drains
__device__ __forceinline__ void st16(void* p, f4v v) {
    asm volatile("global_store_dwordx4 %0, %1, off" :: "v"(p), "v"(v) : "memory");
}
// pinned LDS read: output lives in registers, cannot be rematerialized at use
__device__ __forceinline__ f4v ldsr16(int addr) {
    f4v out;
    asm volatile("ds_read_b128 %0, %1" : "=v"(out) : "v"(addr));
    return out;
}

// ---------------- Kernel A: gx tiled: W in regs, x tile in LDS --------------
// grid = B * (T/64) = 1024 blocks x 192 threads; thread = one output column g
// (dir = g/96). 64 rows per block; per row: 8 LDS broadcast f4 reads + 32 fma.
__global__ __launch_bounds__(192) void gx_kernel(
    const float* __restrict__ a_seq,
    const float* __restrict__ wih_f, const float* __restrict__ bih_f,
    const float* __restrict__ wih_b, const float* __restrict__ bih_b,
    float* __restrict__ gx) {
    __shared__ float xt[64 * 32];
    int blk = blockIdx.x;
    int b = blk >> 3;
    int t0 = (blk & 7) << 6;
    int g = threadIdx.x;            // 0..191
    int dir = (g >= 96) ? 1 : 0;
    int gg = dir ? (g - 96) : g;
    const float* w = dir ? wih_b : wih_f;
    const float* bv = dir ? bih_b : bih_f;

    // stage x tile [64][32] (coalesced float4)
    {
        const float4* src = (const float4*)(a_seq + ((size_t)b * T + t0) * PP);
        float4* dst = (float4*)xt;
        for (int idx = g; idx < 512; idx += 192) dst[idx] = src[idx];
    }
    float wreg[32];
#pragma unroll
    for (int q = 0; q < 8; ++q) {
        float4 wv = *(const float4*)(w + (size_t)gg * PP + q * 4);
        wreg[q * 4 + 0] = wv.x; wreg[q * 4 + 1] = wv.y;
        wreg[q * 4 + 2] = wv.z; wreg[q * 4 + 3] = wv.w;
    }
    float bias = bv[gg];
    __syncthreads();

    float* op = gx + ((size_t)(dir * B + b) * T + t0) * 96 + gg;
#pragma unroll 4
    for (int r = 0; r < 64; ++r) {
        const float4* xr = (const float4*)(xt + r * 32);
        float acc = bias;
#pragma unroll
        for (int q = 0; q < 8; ++q) {
            float4 xv = xr[q];
            acc = fmaf(xv.x, wreg[q * 4 + 0], acc);
            acc = fmaf(xv.y, wreg[q * 4 + 1], acc);
            acc = fmaf(xv.z, wreg[q * 4 + 2], acc);
            acc = fmaf(xv.w, wreg[q * 4 + 3], acc);
        }
        op[(size_t)r * 96] = acc;
    }
}

// ---------------- Kernel B: GRU scan, readlane-broadcast, no LDS ------------
__global__ __launch_bounds__(64) void gru_kernel(
    const float* __restrict__ gx,
    const float* __restrict__ whh_f, const float* __restrict__ bhh_f,
    const float* __restrict__ whh_b, const float* __restrict__ bhh_b,
    float* __restrict__ hseq) {
    int cid = blockIdx.x;            // 0..255 = dir*128 + b
    int b = cid & 127;
    int dir = cid >> 7;
    int l = threadIdx.x;
    int i = l & 31;
    const float* whh = dir ? whh_b : whh_f;
    const float* bhh = dir ? bhh_b : bhh_f;
    const float* gp0 = gx + (size_t)cid * (T * 96);

    float wr[32], wz[32], wn[32];
#pragma unroll
    for (int q = 0; q < 8; ++q) {
        float4 a0 = *(const float4*)(whh + (size_t)i * 32 + q * 4);
        float4 a1 = *(const float4*)(whh + (size_t)(32 + i) * 32 + q * 4);
        float4 a2 = *(const float4*)(whh + (size_t)(64 + i) * 32 + q * 4);
        wr[q * 4 + 0] = a0.x; wr[q * 4 + 1] = a0.y; wr[q * 4 + 2] = a0.z; wr[q * 4 + 3] = a0.w;
        wz[q * 4 + 0] = a1.x; wz[q * 4 + 1] = a1.y; wz[q * 4 + 2] = a1.z; wz[q * 4 + 3] = a1.w;
        wn[q * 4 + 0] = a2.x; wn[q * 4 + 1] = a2.y; wn[q * 4 + 2] = a2.z; wn[q * 4 + 3] = a2.w;
    }
    float bhr = bhh[i], bhz = bhh[32 + i], bhn = bhh[64 + i];

    const float* p = gp0 + (dir ? (T - 1) * 96 : 0);
    int gstep = dir ? -96 : 96;
    int voff = (((dir ? (T - 1) : 0) * B + b) * 64 + dir * 32 + i) * 4;
    int vstep = dir ? -(B * 64 * 4) : (B * 64 * 4);

    float pxr[8], pxz[8], pxn[8];
#pragma unroll
    for (int s = 0; s < 8; ++s) {
        const float* rp = p + s * gstep;
        pxr[s] = rp[i]; pxz[s] = rp[32 + i]; pxn[s] = rp[64 + i];
    }
    float h = 0.f;

#define GSTEP(SLOT) do {                                                       \
        float hr_ = pxr[SLOT] + bhr;                                           \
        float hz_ = pxz[SLOT] + bhz;                                           \
        float hn_ = bhn;                                                       \
        _Pragma("unroll")                                                      \
        for (int jj = 0; jj < 32; ++jj) {                                      \
            float hj_ = __uint_as_float(                                       \
                __builtin_amdgcn_readlane(__float_as_uint(h), jj));            \
            hr_ = fmaf(wr[jj], hj_, hr_);                                      \
            hz_ = fmaf(wz[jj], hj_, hz_);                                      \
            hn_ = fmaf(wn[jj], hj_, hn_);                                      \
        }                                                                      \
        float r_ = __builtin_amdgcn_rcpf(1.f + __expf(-hr_));                  \
        float z_ = __builtin_amdgcn_rcpf(1.f + __expf(-hz_));                  \
        float na_ = fmaf(r_, hn_, pxn[SLOT]);                                  \
        float e2_ = __expf(-2.f * fabsf(na_));                                 \
        float n_ = copysignf((1.f - e2_) * __builtin_amdgcn_rcpf(1.f + e2_), na_); \
        h = fmaf(z_, h - n_, n_);                                              \
        asm volatile("global_store_dword %0, %1, %2"                           \
                     :: "v"(voff), "v"(h), "s"(hseq) : "memory");              \
        voff += vstep;                                                         \
    } while (0)

    for (int tq = 0; tq < 64; ++tq) {
        GSTEP(0); GSTEP(1); GSTEP(2); GSTEP(3);
#pragma unroll
        for (int u = 0; u < 4; ++u) {
            int sc = tq * 8 + 8 + u; if (sc > T - 1) sc = T - 1;
            const float* rp = p + sc * gstep;
            pxr[u] = rp[i]; pxz[u] = rp[32 + i]; pxn[u] = rp[64 + i];
        }
        GSTEP(4); GSTEP(5); GSTEP(6); GSTEP(7);
#pragma unroll
        for (int u = 0; u < 4; ++u) {
            int sc = tq * 8 + 12 + u; if (sc > T - 1) sc = T - 1;
            const float* rp = p + sc * gstep;
            pxr[4 + u] = rp[i]; pxz[4 + u] = rp[32 + i]; pxn[4 + u] = rp[64 + i];
        }
    }
#undef GSTEP
}

// ---------------- Kernel C: logits' = (h_seq @ wl^T + bl) * (1/tau) ---------
__global__ __launch_bounds__(256) void logits_kernel(
    const float* __restrict__ hseq,
    const float* __restrict__ wl, const float* __restrict__ bl,
    const float* __restrict__ wi, const float* __restrict__ bi,
    float* __restrict__ logits, float* __restrict__ initl) {
    int q = threadIdx.x >> 6;
    int tb = blockIdx.x * 4 + q;   // t*B + b
    int g = threadIdx.x & 63;
    __shared__ float hrow[4][64];
    hrow[q][g] = hseq[(size_t)tb * 64 + g];
    __syncthreads();
    float acc = bl[g];
    const float* wrow = wl + (size_t)g * 64;
#pragma unroll
    for (int c = 0; c < 64; ++c) acc = fmaf(wrow[c], hrow[q][c], acc);
    logits[(size_t)tb * 64 + g] = acc * TINV;
    if (tb < B && g < 8) {            // t == 0 blocks, tb == b
        float a2 = bi[g];
        const float* w2 = wi + (size_t)g * 64;
#pragma unroll
        for (int c = 0; c < 64; ++c) a2 = fmaf(w2[c], hrow[q][c], a2);
        initl[tb * 8 + g] = a2;
    }
}

// ---------------- Kernel G: gumbel noise [t][b][8], pre-scaled by 1/tau -----
__global__ __launch_bounds__(256) void gsc_kernel(
    const float* __restrict__ u0, const float* __restrict__ useq,
    float* __restrict__ gs) {
    int id = blockIdx.x * 256 + threadIdx.x;
    if (id >= T * B * KK) return;
    int j = id & 7;
    int b = (id >> 3) & 127;
    int t = id >> 10;
    float u = (t == 0) ? u0[b * 8 + j]
                       : useq[((size_t)b * (T - 1) + (t - 1)) * 8 + j];
    gs[id] = -logf(-logf(u)) * TINV;   // precise logf: u near 1 is ill-conditioned
}

// ---------------- Kernel D: y-only scan, k-split across wave halves ---------
// 4 blocks x 64 lanes; lane r: batch b0+(r&31), k-half r>>5 (k in [h*4,h*4+4)).
// DMA ring + vmcnt(46)/35 discipline byte-identical to the verified round-5
// scheme (9 DMA + 2 stores = 11 vm ops/phase). Per-lane SREAD halved (8+2
// ds_reads); dot = 32 fma + 8 shfl_xor(32) combine; softmax WITHOUT max-sub
// (args bounded: |dot|<~30, gumbel' in [-5.3,27.6] -> exp safe in fp32);
// normalization deferred: carry unnormalized e[8] + sinv; a=fma(dotE,sinv,g').
__global__ __launch_bounds__(64, 1) void scan_kernel(
    const float* __restrict__ logits, const float* __restrict__ initl,
    const float* __restrict__ gs, float* __restrict__ yseq) {
    __shared__ float lds[6][2304];   // 6 slots x (32*64 logits + 32*8 gs)
    int r = threadIdx.x;
    int b0 = blockIdx.x * 32;
    int b = b0 + (r & 31);
    int k15 = r & 15;
    int h8 = (r >> 5) * 8;           // f4v base index of this lane's k-half
    int h4 = (r >> 5) * 4;           // k base of this lane's half

    unsigned ldsU = (unsigned)(unsigned long long)(as3f*)(&lds[0][0]);

    // DMA source offsets, pre-swizzled with the same involution the reads use
    int lof[8];
#pragma unroll
    for (int q = 0; q < 8; ++q) {
        int rr = q * 4 + (r >> 4);         // tile row 0..31
        int cc = r & 15;                   // linear f4v col in LDS
        lof[q] = (((b0 + rr) * 64) + ((cc ^ (rr & 15)) << 2)) << 2;
    }
    int gof;
    {
        int rg = r >> 1;
        int cc = r & 1;
        gof = (((b0 + rg) * 8) + ((cc ^ (rg & 1)) << 2)) << 2;
    }
    unsigned rbase = ldsU + (unsigned)((r & 31) * 256);   // per-lane row base
    unsigned gbase = ldsU + 8192u + (unsigned)((r & 31) * 32);

#define ISSUE(tt, sl) do {                                                   \
        unsigned lb_ = ldsU + (unsigned)((sl) * 9216);                       \
        const char* bt_ = (const char*)logits + (size_t)(tt) * 32768;        \
        const char* gt_ = (const char*)gs + (size_t)(tt) * 4096;             \
        dma16(lb_ + 0 * 1024u, lof[0], bt_);                                 \
        dma16(lb_ + 1 * 1024u, lof[1], bt_);                                 \
        dma16(lb_ + 2 * 1024u, lof[2], bt_);                                 \
        dma16(lb_ + 3 * 1024u, lof[3], bt_);                                 \
        dma16(lb_ + 4 * 1024u, lof[4], bt_);                                 \
        dma16(lb_ + 5 * 1024u, lof[5], bt_);                                 \
        dma16(lb_ + 6 * 1024u, lof[6], bt_);                                 \
        dma16(lb_ + 7 * 1024u, lof[7], bt_);                                 \
        dma16(lb_ + 8192u, gof, gt_);                                        \
    } while (0)

// read only this lane's k-half rows (8 f4v) + gs (2 f4v)
#define SREAD(LL, GA, GB, tt) do {                                           \
        int so_ = ((tt) % 6) * 9216;                                         \
        _Pragma("unroll")                                                    \
        for (int m_ = 0; m_ < 8; ++m_)                                       \
            LL[m_] = ldsr16((int)(rbase + so_ + (((m_ + h8) ^ k15) << 4)));  \
        GA = ldsr16((int)(gbase + so_ + ((r & 1) << 4)));                    \
        GB = ldsr16((int)(gbase + so_ + (((r & 1) ^ 1) << 4)));              \
    } while (0)

#define LWAIT() do {                                                         \
        asm volatile("s_waitcnt lgkmcnt(0)" ::: "memory");                   \
        __builtin_amdgcn_sched_barrier(0);                                   \
    } while (0)

#define SCOMP(LL, GA, GB, tt) do {                                           \
        float pl_[8];                                                        \
        _Pragma("unroll")                                                    \
        for (int j_ = 0; j_ < 8; ++j_) pl_[j_] = 0.f;                        \
        _Pragma("unroll")                                                    \
        for (int kk_ = 0; kk_ < 4; ++kk_) {                                  \
            f4v w0_ = LL[2 * kk_], w1_ = LL[2 * kk_ + 1];                    \
            float ek_ = e[h4 + kk_];                                         \
            pl_[0] = fmaf(ek_, w0_.x, pl_[0]); pl_[1] = fmaf(ek_, w0_.y, pl_[1]); \
            pl_[2] = fmaf(ek_, w0_.z, pl_[2]); pl_[3] = fmaf(ek_, w0_.w, pl_[3]); \
            pl_[4] = fmaf(ek_, w1_.x, pl_[4]); pl_[5] = fmaf(ek_, w1_.y, pl_[5]); \
            pl_[6] = fmaf(ek_, w1_.z, pl_[6]); pl_[7] = fmaf(ek_, w1_.w, pl_[7]); \
        }                                                                    \
        float gg_[8] = {GA.x, GA.y, GA.z, GA.w, GB.x, GB.y, GB.z, GB.w};     \
        float ss_ = 0.f;                                                     \
        _Pragma("unroll")                                                    \
        for (int j_ = 0; j_ < 8; ++j_) {                                     \
            float d_ = pl_[j_] + __shfl_xor(pl_[j_], 32, 64);                \
            float a_ = fmaf(d_, sinv, gg_[j_]);                              \
            e[j_] = __expf(a_);                                              \
            ss_ += e[j_];                                                    \
        }                                                                    \
        sinv = __builtin_amdgcn_rcpf(ss_);                                   \
        if (r < 32) {                                                        \
            f4v v0_ = (f4v){e[0] * sinv, e[1] * sinv, e[2] * sinv, e[3] * sinv}; \
            f4v v1_ = (f4v){e[4] * sinv, e[5] * sinv, e[6] * sinv, e[7] * sinv}; \
            st16(&yp[2 * (tt)], v0_);                                        \
            st16(&yp[2 * (tt) + 1], v1_);                                    \
        }                                                                    \
    } while (0)

    f4v* yp = (f4v*)(yseq + (size_t)b * T * 8);
    float e[8];
    float sinv;

    // ---- t = 0 from initl + gs[0] (plain loads, compiler-tracked) ----
    {
        const f4v* il4 = (const f4v*)(initl + b * 8);
        f4v i0 = il4[0], i1 = il4[1];
        const f4v* g4 = (const f4v*)(gs + b * 8);
        f4v G0 = g4[0], G1 = g4[1];
        float a[8];
        a[0] = fmaf(i0.x, TINV, G0.x); a[1] = fmaf(i0.y, TINV, G0.y);
        a[2] = fmaf(i0.z, TINV, G0.z); a[3] = fmaf(i0.w, TINV, G0.w);
        a[4] = fmaf(i1.x, TINV, G1.x); a[5] = fmaf(i1.y, TINV, G1.y);
        a[6] = fmaf(i1.z, TINV, G1.z); a[7] = fmaf(i1.w, TINV, G1.w);
        float ssum = 0.f;
#pragma unroll
        for (int j = 0; j < 8; ++j) { e[j] = __expf(a[j]); ssum += e[j]; }
        sinv = __builtin_amdgcn_rcpf(ssum);
    }
    f4v y0v = (f4v){e[0] * sinv, e[1] * sinv, e[2] * sinv, e[3] * sinv};
    f4v y1v = (f4v){e[4] * sinv, e[5] * sinv, e[6] * sinv, e[7] * sinv};

    // ---- prologue: 5 phases (ISSUE + 2 dup y0 stores) = uniform 11-op shape
#pragma unroll
    for (int p = 1; p <= 5; ++p) {
        ISSUE(p, p);
        if (r < 32) { st16(&yp[0], y0v); st16(&yp[1], y1v); }
    }

    f4v LA[8], LB[8], gaA, gbA, gaB, gbB;

    // slot 1 done when <=46 of the 55 prologue ops outstanding
    asm volatile("s_waitcnt vmcnt(46)" ::: "memory");
    __builtin_amdgcn_sched_barrier(0);
    SREAD(LA, gaA, gbA, 1);

    for (int t = 1; t < T - 1; t += 2) {
        asm volatile("s_waitcnt vmcnt(35)" ::: "memory");
        __builtin_amdgcn_sched_barrier(0);
        { int tp = t + 5; if (tp > T - 1) tp = T - 1; ISSUE(tp, (t + 5) % 6); }
        LWAIT();                       // LA (or prev LB) reads complete
        SREAD(LB, gaB, gbB, t + 1);
        SCOMP(LA, gaA, gbA, t);

        asm volatile("s_waitcnt vmcnt(35)" ::: "memory");
        __builtin_amdgcn_sched_barrier(0);
        { int tp = t + 6; if (tp > T - 1) tp = T - 1; ISSUE(tp, (t + 6) % 6); }
        LWAIT();
        SREAD(LA, gaA, gbA, t + 2);
        SCOMP(LB, gaB, gbB, t + 1);
    }
    LWAIT();
    SCOMP(LA, gaA, gbA, T - 1);
#undef ISSUE
#undef SREAD
#undef LWAIT
#undef SCOMP
}

// ---------------- Kernel E: parallel log_q / log_p --------------------------
__global__ __launch_bounds__(256) void lqlp_kernel(
    const float* __restrict__ logits, const float* __restrict__ initl,
    const float* __restrict__ yseq,
    float* __restrict__ logq, float* __restrict__ logp) {
    int tid = blockIdx.x * 256 + threadIdx.x;   // tid = b*T + t
    if (tid >= B * T) return;
    int b = tid >> 9;
    int t = tid & (T - 1);

    const float4* yt4 = (const float4*)(yseq + (size_t)tid * 8);
    float4 y0 = yt4[0], y1 = yt4[1];
    float yt[8] = {y0.x, y0.y, y0.z, y0.w, y1.x, y1.y, y1.z, y1.w};

    float l[8];
    float lp;
    if (t == 0) {
        const float4* il4 = (const float4*)(initl + b * 8);
        float4 i0 = il4[0], i1 = il4[1];
        l[0] = i0.x; l[1] = i0.y; l[2] = i0.z; l[3] = i0.w;
        l[4] = i1.x; l[5] = i1.y; l[6] = i1.z; l[7] = i1.w;
        float sy = ((yt[0] + yt[1]) + (yt[2] + yt[3])) + ((yt[4] + yt[5]) + (yt[6] + yt[7]));
        lp = LOG_INV_K * sy;
    } else {
        const float4* yp4 = (const float4*)(yseq + (size_t)tid * 8 - 8);
        float4 p0 = yp4[0], p1 = yp4[1];
        float ypv[8] = {p0.x, p0.y, p0.z, p0.w, p1.x, p1.y, p1.z, p1.w};
        const float4* L4 = (const float4*)(logits + ((size_t)t * B + b) * 64);
#pragma unroll
        for (int j = 0; j < 8; ++j) l[j] = 0.f;
#pragma unroll
        for (int k = 0; k < 8; ++k) {
            float4 w0 = L4[2 * k], w1 = L4[2 * k + 1];
            float yk = ypv[k];
            l[0] = fmaf(yk, w0.x, l[0]); l[1] = fmaf(yk, w0.y, l[1]);
            l[2] = fmaf(yk, w0.z, l[2]); l[3] = fmaf(yk, w0.w, l[3]);
            l[4] = fmaf(yk, w1.x, l[4]); l[5] = fmaf(yk, w1.y, l[5]);
            l[6] = fmaf(yk, w1.z, l[6]); l[7] = fmaf(yk, w1.w, l[7]);
        }
#pragma unroll
        for (int j = 0; j < 8; ++j) l[j] *= 0.5f;   // stored logits are pre-scaled by 1/tau
        float sy = ((ypv[0] + ypv[1]) + (ypv[2] + ypv[3])) + ((ypv[4] + ypv[5]) + (ypv[6] + ypv[7]));
        float acc = 0.f;
#pragma unroll
        for (int j = 0; j < 8; ++j) {
            float tp = fmaf(DPS, ypv[j], OFFV * sy);
            acc = fmaf(yt[j], logf(fmaxf(tp, 1e-8f)), acc);
        }
        lp = acc;
    }
    float m = fmaxf(fmaxf(fmaxf(l[0], l[1]), fmaxf(l[2], l[3])),
                    fmaxf(fmaxf(l[4], l[5]), fmaxf(l[6], l[7])));
    float se = 0.f;
#pragma unroll
    for (int j = 0; j < 8; ++j) se += __expf(l[j] - m);
    float lse = m + logf(se);
    float lq = 0.f;
#pragma unroll
    for (int j = 0; j < 8; ++j) lq = fmaf(yt[j], l[j] - lse, lq);
    logq[tid] = lq;
    logp[tid] = lp;
}

// ---------------- Kernel F: output einsums + C broadcast (float4 stores) ----
__global__ __launch_bounds__(128) void out_kernel(
    const float* __restrict__ yseq,
    const float* __restrict__ A, const float* __restrict__ Bm,
    const float* __restrict__ C, const float* __restrict__ Q,
    float4* __restrict__ out4) {
    int bt = blockIdx.x;   // b*T + t
    __shared__ float ys[8];
    if (threadIdx.x < 8) ys[threadIdx.x] = yseq[(size_t)bt * 8 + threadIdx.x];
    __syncthreads();
    float yr[8];
#pragma unroll
    for (int k = 0; k < 8; ++k) yr[k] = ys[k];

    const float4* A4 = (const float4*)A;
    const float4* B4 = (const float4*)Bm;
    const float4* Q4 = (const float4*)Q;
    const float4* C4 = (const float4*)C;

    for (int q = threadIdx.x; q < 288; q += 128) {
        float4 v = make_float4(0.f, 0.f, 0.f, 0.f);
        size_t oidx;
        if (q < 64) {
#pragma unroll
            for (int k = 0; k < 8; ++k) {
                float4 w = A4[k * 64 + q];
                v.x = fmaf(yr[k], w.x, v.x);
                v.y = fmaf(yr[k], w.y, v.y);
                v.z = fmaf(yr[k], w.z, v.z);
                v.w = fmaf(yr[k], w.w, v.w);
            }
            oidx = (size_t)(OUT_A / 4) + (size_t)bt * 64 + q;
        } else if (q < 96) {
            int qb = q - 64;
#pragma unroll
            for (int k = 0; k < 8; ++k) {
                float4 w = B4[k * 32 + qb];
                v.x = fmaf(yr[k], w.x, v.x);
                v.y = fmaf(yr[k], w.y, v.y);
                v.z = fmaf(yr[k], w.z, v.z);
                v.w = fmaf(yr[k], w.w, v.w);
            }
            oidx = (size_t)(OUT_B / 4) + (size_t)bt * 32 + qb;
        } else if (q < 160) {
            int qq = q - 96;
#pragma unroll
            for (int k = 0; k < 8; ++k) {
                float4 w = Q4[k * 64 + qq];
                v.x = fmaf(yr[k], w.x, v.x);
                v.y = fmaf(yr[k], w.y, v.y);
                v.z = fmaf(yr[k], w.z, v.z);
                v.w = fmaf(yr[k], w.w, v.w);
            }
            oidx = (size_t)(OUT_Q / 4) + (size_t)bt * 64 + qq;
        } else {
            int qc = q - 160;
            v = C4[qc];
            oidx = (size_t)(OUT_C / 4) + (size_t)bt * 128 + qc;
        }
        out4[oidx] = v;
    }
}

extern "C" void kernel_launch(void* const* d_in, const int* in_sizes, int n_in,
                              void* d_out, int out_size, void* d_ws, size_t ws_size,
                              hipStream_t stream) {
    const float* a_seq = (const float*)d_in[0];
    const float* A     = (const float*)d_in[1];
    const float* Bmat  = (const float*)d_in[2];
    const float* C     = (const float*)d_in[3];
    const float* Q     = (const float*)d_in[4];
    const float* wih_f = (const float*)d_in[5];
    const float* whh_f = (const float*)d_in[6];
    const float* bih_f = (const float*)d_in[7];
    const float* bhh_f = (const float*)d_in[8];
    const float* wih_b = (const float*)d_in[9];
    const float* whh_b = (const float*)d_in[10];
    const float* bih_b = (const float*)d_in[11];
    const float* bhh_b = (const float*)d_in[12];
    const float* wl    = (const float*)d_in[13];
    const float* bl    = (const float*)d_in[14];
    const float* wi    = (const float*)d_in[15];
    const float* bi    = (const float*)d_in[16];
    const float* u0    = (const float*)d_in[17];
    const float* useq  = (const float*)d_in[18];

    float* ws = (float*)d_ws;
    float* gx     = ws + WS_GX;
    float* gsb    = ws + WS_GS;       // aliases gx dir=1 half (written after GRU)
    float* hseq   = ws + WS_HSEQ;
    float* logits = ws + WS_LOGITS;   // aliases gx dir=0 half (written after GRU)
    float* initl  = ws + WS_INIT;
    float* yseq   = ws + WS_YSEQ;

    float* outf = (float*)d_out;
    float* logq = outf + OUT_LQ;
    float* logp = outf + OUT_LP;

    gx_kernel<<<B * (T / 64), 192, 0, stream>>>(a_seq, wih_f, bih_f, wih_b, bih_b, gx);
    gru_kernel<<<256, 64, 0, stream>>>(gx, whh_f, bhh_f, whh_b, bhh_b, hseq);
    {
        int total = B * T * KK;
        gsc_kernel<<<(total + 255) / 256, 256, 0, stream>>>(u0, useq, gsb);
    }
    logits_kernel<<<T * B / 4, 256, 0, stream>>>(hseq, wl, bl, wi, bi, logits, initl);
    scan_kernel<<<4, 64, 0, stream>>>(logits, initl, gsb, yseq);
    lqlp_kernel<<<(B * T + 255) / 256, 256, 0, stream>>>(logits, initl, yseq, logq, logp);
    out_kernel<<<B * T, 128, 0, stream>>>(yseq, A, Bmat, C, Q, (float4*)d_out);
}

// Round 9
// 581.810 us; speedup vs baseline: 1.2224x; 1.2224x over previous
//
#include <hip/hip_runtime.h>
#include <math.h>

#define T 512
#define B 128
#define KK 8
#define HH 32
#define PP 32

// ws layout (floats)
#define WS_GX    0             /* gx [dir*B+b][t][96] = 12582912 floats */
#define WS_GS    6291456       /* alias gx dir=1 half: gumbel noise [t][b][8], written after GRU */
#define WS_HSEQ  12582912
#define WS_LOGITS 0            /* alias gx dir=0 half: scaled logits [t][b][64], written after GRU */
#define WS_INIT  16777216
#define WS_YSEQ  16778240

// d_out layout (floats)
#define OUT_A    0
#define OUT_B    16777216
#define OUT_C    25165824
#define OUT_Q    58720256
#define OUT_LQ   75497472
#define OUT_LP   75563008

#define TINV 2.0f
#define PSTAY 0.9f
#define OFFV (0.1f / 7.0f)
#define DPS (PSTAY - OFFV)
#define LOG_INV_K (-2.0794415416798357f)

typedef float f4v __attribute__((ext_vector_type(4)));
typedef __attribute__((address_space(3))) float as3f;

// async DMA global->LDS, 16B/lane, opaque to compiler (no auto waitcnt insertion)
__device__ __forceinline__ void dma16(unsigned ldsbyte, int voffbyte, const void* sbase) {
    asm volatile("s_mov_b32 m0, %0\n\t"
                 "global_load_lds_dwordx4 %1, %2"
                 :: "s"(ldsbyte), "v"(voffbyte), "s"(sbase)
                 : "memory");
}
// stores kept in asm: compiler does not track them -> no per-iter vmcnt drains
__device__ __forceinline__ void st16(void* p, f4v v) {
    asm volatile("global_store_dwordx4 %0, %1, off" :: "v"(p), "v"(v) : "memory");
}
// pinned LDS read: output lives in registers, cannot be rematerialized at use
__device__ __forceinline__ f4v ldsr16(int addr) {
    f4v out;
    asm volatile("ds_read_b128 %0, %1" : "=v"(out) : "v"(addr));
    return out;
}

// ---------------- Kernel A: gx tiled: W in regs, x tile in LDS --------------
__global__ __launch_bounds__(192) void gx_kernel(
    const float* __restrict__ a_seq,
    const float* __restrict__ wih_f, const float* __restrict__ bih_f,
    const float* __restrict__ wih_b, const float* __restrict__ bih_b,
    float* __restrict__ gx) {
    __shared__ float xt[64 * 32];
    int blk = blockIdx.x;
    int b = blk >> 3;
    int t0 = (blk & 7) << 6;
    int g = threadIdx.x;            // 0..191
    int dir = (g >= 96) ? 1 : 0;
    int gg = dir ? (g - 96) : g;
    const float* w = dir ? wih_b : wih_f;
    const float* bv = dir ? bih_b : bih_f;

    {
        const float4* src = (const float4*)(a_seq + ((size_t)b * T + t0) * PP);
        float4* dst = (float4*)xt;
        for (int idx = g; idx < 512; idx += 192) dst[idx] = src[idx];
    }
    float wreg[32];
#pragma unroll
    for (int q = 0; q < 8; ++q) {
        float4 wv = *(const float4*)(w + (size_t)gg * PP + q * 4);
        wreg[q * 4 + 0] = wv.x; wreg[q * 4 + 1] = wv.y;
        wreg[q * 4 + 2] = wv.z; wreg[q * 4 + 3] = wv.w;
    }
    float bias = bv[gg];
    __syncthreads();

    float* op = gx + ((size_t)(dir * B + b) * T + t0) * 96 + gg;
#pragma unroll 4
    for (int r = 0; r < 64; ++r) {
        const float4* xr = (const float4*)(xt + r * 32);
        float acc = bias;
#pragma unroll
        for (int q = 0; q < 8; ++q) {
            float4 xv = xr[q];
            acc = fmaf(xv.x, wreg[q * 4 + 0], acc);
            acc = fmaf(xv.y, wreg[q * 4 + 1], acc);
            acc = fmaf(xv.z, wreg[q * 4 + 2], acc);
            acc = fmaf(xv.w, wreg[q * 4 + 3], acc);
        }
        op[(size_t)r * 96] = acc;
    }
}

// ---------------- Kernel B: GRU scan, readlane-broadcast, no LDS ------------
__global__ __launch_bounds__(64) void gru_kernel(
    const float* __restrict__ gx,
    const float* __restrict__ whh_f, const float* __restrict__ bhh_f,
    const float* __restrict__ whh_b, const float* __restrict__ bhh_b,
    float* __restrict__ hseq) {
    int cid = blockIdx.x;            // 0..255 = dir*128 + b
    int b = cid & 127;
    int dir = cid >> 7;
    int l = threadIdx.x;
    int i = l & 31;
    const float* whh = dir ? whh_b : whh_f;
    const float* bhh = dir ? bhh_b : bhh_f;
    const float* gp0 = gx + (size_t)cid * (T * 96);

    float wr[32], wz[32], wn[32];
#pragma unroll
    for (int q = 0; q < 8; ++q) {
        float4 a0 = *(const float4*)(whh + (size_t)i * 32 + q * 4);
        float4 a1 = *(const float4*)(whh + (size_t)(32 + i) * 32 + q * 4);
        float4 a2 = *(const float4*)(whh + (size_t)(64 + i) * 32 + q * 4);
        wr[q * 4 + 0] = a0.x; wr[q * 4 + 1] = a0.y; wr[q * 4 + 2] = a0.z; wr[q * 4 + 3] = a0.w;
        wz[q * 4 + 0] = a1.x; wz[q * 4 + 1] = a1.y; wz[q * 4 + 2] = a1.z; wz[q * 4 + 3] = a1.w;
        wn[q * 4 + 0] = a2.x; wn[q * 4 + 1] = a2.y; wn[q * 4 + 2] = a2.z; wn[q * 4 + 3] = a2.w;
    }
    float bhr = bhh[i], bhz = bhh[32 + i], bhn = bhh[64 + i];

    const float* p = gp0 + (dir ? (T - 1) * 96 : 0);
    int gstep = dir ? -96 : 96;
    int voff = (((dir ? (T - 1) : 0) * B + b) * 64 + dir * 32 + i) * 4;
    int vstep = dir ? -(B * 64 * 4) : (B * 64 * 4);

    float pxr[8], pxz[8], pxn[8];
#pragma unroll
    for (int s = 0; s < 8; ++s) {
        const float* rp = p + s * gstep;
        pxr[s] = rp[i]; pxz[s] = rp[32 + i]; pxn[s] = rp[64 + i];
    }
    float h = 0.f;

#define GSTEP(SLOT) do {                                                       \
        float hr_ = pxr[SLOT] + bhr;                                           \
        float hz_ = pxz[SLOT] + bhz;                                           \
        float hn_ = bhn;                                                       \
        _Pragma("unroll")                                                      \
        for (int jj = 0; jj < 32; ++jj) {                                      \
            float hj_ = __uint_as_float(                                       \
                __builtin_amdgcn_readlane(__float_as_uint(h), jj));            \
            hr_ = fmaf(wr[jj], hj_, hr_);                                      \
            hz_ = fmaf(wz[jj], hj_, hz_);                                      \
            hn_ = fmaf(wn[jj], hj_, hn_);                                      \
        }                                                                      \
        float r_ = __builtin_amdgcn_rcpf(1.f + __expf(-hr_));                  \
        float z_ = __builtin_amdgcn_rcpf(1.f + __expf(-hz_));                  \
        float na_ = fmaf(r_, hn_, pxn[SLOT]);                                  \
        float e2_ = __expf(-2.f * fabsf(na_));                                 \
        float n_ = copysignf((1.f - e2_) * __builtin_amdgcn_rcpf(1.f + e2_), na_); \
        h = fmaf(z_, h - n_, n_);                                              \
        asm volatile("global_store_dword %0, %1, %2"                           \
                     :: "v"(voff), "v"(h), "s"(hseq) : "memory");              \
        voff += vstep;                                                         \
    } while (0)

    for (int tq = 0; tq < 64; ++tq) {
        GSTEP(0); GSTEP(1); GSTEP(2); GSTEP(3);
#pragma unroll
        for (int u = 0; u < 4; ++u) {
            int sc = tq * 8 + 8 + u; if (sc > T - 1) sc = T - 1;
            const float* rp = p + sc * gstep;
            pxr[u] = rp[i]; pxz[u] = rp[32 + i]; pxn[u] = rp[64 + i];
        }
        GSTEP(4); GSTEP(5); GSTEP(6); GSTEP(7);
#pragma unroll
        for (int u = 0; u < 4; ++u) {
            int sc = tq * 8 + 12 + u; if (sc > T - 1) sc = T - 1;
            const float* rp = p + sc * gstep;
            pxr[4 + u] = rp[i]; pxz[4 + u] = rp[32 + i]; pxn[4 + u] = rp[64 + i];
        }
    }
#undef GSTEP
}

// ---------------- Kernel C: logits' = (h_seq @ wl^T + bl) * (1/tau) ---------
__global__ __launch_bounds__(256) void logits_kernel(
    const float* __restrict__ hseq,
    const float* __restrict__ wl, const float* __restrict__ bl,
    const float* __restrict__ wi, const float* __restrict__ bi,
    float* __restrict__ logits, float* __restrict__ initl) {
    int q = threadIdx.x >> 6;
    int tb = blockIdx.x * 4 + q;   // t*B + b
    int g = threadIdx.x & 63;
    __shared__ float hrow[4][64];
    hrow[q][g] = hseq[(size_t)tb * 64 + g];
    __syncthreads();
    float acc = bl[g];
    const float* wrow = wl + (size_t)g * 64;
#pragma unroll
    for (int c = 0; c < 64; ++c) acc = fmaf(wrow[c], hrow[q][c], acc);
    logits[(size_t)tb * 64 + g] = acc * TINV;
    if (tb < B && g < 8) {            // t == 0 blocks, tb == b
        float a2 = bi[g];
        const float* w2 = wi + (size_t)g * 64;
#pragma unroll
        for (int c = 0; c < 64; ++c) a2 = fmaf(w2[c], hrow[q][c], a2);
        initl[tb * 8 + g] = a2;
    }
}

// ---------------- Kernel G: gumbel noise [t][b][8], pre-scaled by 1/tau -----
__global__ __launch_bounds__(256) void gsc_kernel(
    const float* __restrict__ u0, const float* __restrict__ useq,
    float* __restrict__ gs) {
    int id = blockIdx.x * 256 + threadIdx.x;
    if (id >= T * B * KK) return;
    int j = id & 7;
    int b = (id >> 3) & 127;
    int t = id >> 10;
    float u = (t == 0) ? u0[b * 8 + j]
                       : useq[((size_t)b * (T - 1) + (t - 1)) * 8 + j];
    gs[id] = -logf(-logf(u)) * TINV;   // precise logf: u near 1 is ill-conditioned
}

// ---------------- Kernel D: y-only scan, producer/consumer wave split -------
// 4 blocks x 128 threads. Wave 1 = DMA producer: ISSUE(t+5) each phase, own
// loads-only vmcnt FIFO -> vmcnt(27) proves slot t+1 landed (in-order retire,
// m135), then s_barrier. Wave 0 = consumer: raw s_barrier -> lgkmcnt(0) ->
// SREAD(t+1) -> SCOMP(t) + 2 asm stores; NO vm loads in its FIFO so it never
// waits vmcnt. Softmax: no max-sub (args bounded ~|50| << 88), deferred
// normalization (carry unnormalized e[8] + sinv; dot uses e, result * sinv
// folded into the gumbel-add fma). Both waves hit exactly 512 s_barriers.
__global__ __launch_bounds__(128, 1) void scan_kernel(
    const float* __restrict__ logits, const float* __restrict__ initl,
    const float* __restrict__ gs, float* __restrict__ yseq) {
    __shared__ float lds[6][2304];   // 6 slots x (32*64 logits + 32*8 gs)
    int tid = threadIdx.x;
    int wave = tid >> 6;
    int r = tid & 63;
    int b0 = blockIdx.x * 32;
    int b = b0 + (r & 31);
    int k15 = r & 15;

    unsigned ldsU = (unsigned)(unsigned long long)(as3f*)(&lds[0][0]);

#define ISSUE(tt, sl) do {                                                   \
        unsigned lb_ = ldsU + (unsigned)((sl) * 9216);                       \
        const char* bt_ = (const char*)logits + (size_t)(tt) * 32768;        \
        const char* gt_ = (const char*)gs + (size_t)(tt) * 4096;             \
        dma16(lb_ + 0 * 1024u, lof[0], bt_);                                 \
        dma16(lb_ + 1 * 1024u, lof[1], bt_);                                 \
        dma16(lb_ + 2 * 1024u, lof[2], bt_);                                 \
        dma16(lb_ + 3 * 1024u, lof[3], bt_);                                 \
        dma16(lb_ + 4 * 1024u, lof[4], bt_);                                 \
        dma16(lb_ + 5 * 1024u, lof[5], bt_);                                 \
        dma16(lb_ + 6 * 1024u, lof[6], bt_);                                 \
        dma16(lb_ + 7 * 1024u, lof[7], bt_);                                 \
        dma16(lb_ + 8192u, gof, gt_);                                        \
    } while (0)

    if (wave == 1) {
        // ---------------- DMA producer wave ----------------
        int lof[8];
#pragma unroll
        for (int q = 0; q < 8; ++q) {
            int rr = q * 4 + (r >> 4);         // tile row 0..31
            int cc = r & 15;                   // linear f4v col in LDS
            lof[q] = (((b0 + rr) * 64) + ((cc ^ (rr & 15)) << 2)) << 2;
        }
        int gof;
        {
            int rg = r >> 1;
            int cc = r & 1;
            gof = (((b0 + rg) * 8) + ((cc ^ (rg & 1)) << 2)) << 2;
        }
#pragma unroll
        for (int p = 1; p <= 5; ++p) ISSUE(p, p);
        asm volatile("s_waitcnt vmcnt(36)" ::: "memory");   // slot 1 landed
        __builtin_amdgcn_s_barrier();                        // #0
        for (int t = 1; t < T; ++t) {
            asm volatile("s_waitcnt vmcnt(27)" ::: "memory"); // slot t+1 landed
            __builtin_amdgcn_s_barrier();                     // #t
            int tp = t + 5; if (tp > T - 1) tp = T - 1;
            ISSUE(tp, (t + 5) % 6);
        }
        return;
    }

    // ---------------- compute consumer wave ----------------
    unsigned rbase = ldsU + (unsigned)((r & 31) * 256);
    unsigned gbase = ldsU + 8192u + (unsigned)((r & 31) * 32);

#define SREAD(LL, GA, GB, tt) do {                                           \
        int so_ = ((tt) % 6) * 9216;                                         \
        _Pragma("unroll")                                                    \
        for (int m_ = 0; m_ < 16; ++m_)                                      \
            LL[m_] = ldsr16((int)(rbase + so_ + ((m_ ^ k15) << 4)));         \
        GA = ldsr16((int)(gbase + so_ + ((r & 1) << 4)));                    \
        GB = ldsr16((int)(gbase + so_ + (((r & 1) ^ 1) << 4)));              \
    } while (0)

#define LWAIT() do {                                                         \
        asm volatile("s_waitcnt lgkmcnt(0)" ::: "memory");                   \
        __builtin_amdgcn_sched_barrier(0);                                   \
    } while (0)

#define SCOMP(LL, GA, GB, tt) do {                                           \
        float pl_[8];                                                        \
        _Pragma("unroll")                                                    \
        for (int j_ = 0; j_ < 8; ++j_) pl_[j_] = 0.f;                        \
        _Pragma("unroll")                                                    \
        for (int k_ = 0; k_ < 8; ++k_) {                                     \
            f4v w0_ = LL[2 * k_], w1_ = LL[2 * k_ + 1];                      \
            float ek_ = e[k_];                                               \
            pl_[0] = fmaf(ek_, w0_.x, pl_[0]); pl_[1] = fmaf(ek_, w0_.y, pl_[1]); \
            pl_[2] = fmaf(ek_, w0_.z, pl_[2]); pl_[3] = fmaf(ek_, w0_.w, pl_[3]); \
            pl_[4] = fmaf(ek_, w1_.x, pl_[4]); pl_[5] = fmaf(ek_, w1_.y, pl_[5]); \
            pl_[6] = fmaf(ek_, w1_.z, pl_[6]); pl_[7] = fmaf(ek_, w1_.w, pl_[7]); \
        }                                                                    \
        float gg_[8] = {GA.x, GA.y, GA.z, GA.w, GB.x, GB.y, GB.z, GB.w};     \
        float ss_ = 0.f;                                                     \
        _Pragma("unroll")                                                    \
        for (int j_ = 0; j_ < 8; ++j_) {                                     \
            float a_ = fmaf(pl_[j_], sinv, gg_[j_]);                         \
            e[j_] = __expf(a_);                                              \
            ss_ += e[j_];                                                    \
        }                                                                    \
        sinv = __builtin_amdgcn_rcpf(ss_);                                   \
        if (r < 32) {                                                        \
            f4v v0_ = (f4v){e[0] * sinv, e[1] * sinv, e[2] * sinv, e[3] * sinv}; \
            f4v v1_ = (f4v){e[4] * sinv, e[5] * sinv, e[6] * sinv, e[7] * sinv}; \
            st16(&yp[2 * (tt)], v0_);                                        \
            st16(&yp[2 * (tt) + 1], v1_);                                    \
        }                                                                    \
    } while (0)

    f4v* yp = (f4v*)(yseq + (size_t)b * T * 8);
    float e[8];
    float sinv;

    // ---- t = 0 from initl + gs[0] (plain loads, compiler-tracked) ----
    {
        const f4v* il4 = (const f4v*)(initl + b * 8);
        f4v i0 = il4[0], i1 = il4[1];
        const f4v* g4 = (const f4v*)(gs + b * 8);
        f4v G0 = g4[0], G1 = g4[1];
        float a[8];
        a[0] = fmaf(i0.x, TINV, G0.x); a[1] = fmaf(i0.y, TINV, G0.y);
        a[2] = fmaf(i0.z, TINV, G0.z); a[3] = fmaf(i0.w, TINV, G0.w);
        a[4] = fmaf(i1.x, TINV, G1.x); a[5] = fmaf(i1.y, TINV, G1.y);
        a[6] = fmaf(i1.z, TINV, G1.z); a[7] = fmaf(i1.w, TINV, G1.w);
        float ssum = 0.f;
#pragma unroll
        for (int j = 0; j < 8; ++j) { e[j] = __expf(a[j]); ssum += e[j]; }
        sinv = __builtin_amdgcn_rcpf(ssum);
        if (r < 32) {
            f4v y0v = (f4v){e[0] * sinv, e[1] * sinv, e[2] * sinv, e[3] * sinv};
            f4v y1v = (f4v){e[4] * sinv, e[5] * sinv, e[6] * sinv, e[7] * sinv};
            st16(&yp[0], y0v);
            st16(&yp[1], y1v);
        }
    }

    f4v LA[16], LB[16], gaA, gbA, gaB, gbB;

    __builtin_amdgcn_s_barrier();      // #0: slot 1 landed (producer vmcnt(36))
    SREAD(LA, gaA, gbA, 1);

    for (int t = 1; t < T - 1; t += 2) {
        __builtin_amdgcn_s_barrier();  // #t: slot t+1 landed
        LWAIT();                       // prior phase's SREAD retired
        SREAD(LB, gaB, gbB, t + 1);
        SCOMP(LA, gaA, gbA, t);

        __builtin_amdgcn_s_barrier();  // #t+1: slot t+2 landed
        LWAIT();
        SREAD(LA, gaA, gbA, t + 2);
        SCOMP(LB, gaB, gbB, t + 1);
    }
    __builtin_amdgcn_s_barrier();      // #511
    LWAIT();
    SCOMP(LA, gaA, gbA, T - 1);
#undef ISSUE
#undef SREAD
#undef LWAIT
#undef SCOMP
}

// ---------------- Kernel E: parallel log_q / log_p --------------------------
__global__ __launch_bounds__(256) void lqlp_kernel(
    const float* __restrict__ logits, const float* __restrict__ initl,
    const float* __restrict__ yseq,
    float* __restrict__ logq, float* __restrict__ logp) {
    int tid = blockIdx.x * 256 + threadIdx.x;   // tid = b*T + t
    if (tid >= B * T) return;
    int b = tid >> 9;
    int t = tid & (T - 1);

    const float4* yt4 = (const float4*)(yseq + (size_t)tid * 8);
    float4 y0 = yt4[0], y1 = yt4[1];
    float yt[8] = {y0.x, y0.y, y0.z, y0.w, y1.x, y1.y, y1.z, y1.w};

    float l[8];
    float lp;
    if (t == 0) {
        const float4* il4 = (const float4*)(initl + b * 8);
        float4 i0 = il4[0], i1 = il4[1];
        l[0] = i0.x; l[1] = i0.y; l[2] = i0.z; l[3] = i0.w;
        l[4] = i1.x; l[5] = i1.y; l[6] = i1.z; l[7] = i1.w;
        float sy = ((yt[0] + yt[1]) + (yt[2] + yt[3])) + ((yt[4] + yt[5]) + (yt[6] + yt[7]));
        lp = LOG_INV_K * sy;
    } else {
        const float4* yp4 = (const float4*)(yseq + (size_t)tid * 8 - 8);
        float4 p0 = yp4[0], p1 = yp4[1];
        float ypv[8] = {p0.x, p0.y, p0.z, p0.w, p1.x, p1.y, p1.z, p1.w};
        const float4* L4 = (const float4*)(logits + ((size_t)t * B + b) * 64);
#pragma unroll
        for (int j = 0; j < 8; ++j) l[j] = 0.f;
#pragma unroll
        for (int k = 0; k < 8; ++k) {
            float4 w0 = L4[2 * k], w1 = L4[2 * k + 1];
            float yk = ypv[k];
            l[0] = fmaf(yk, w0.x, l[0]); l[1] = fmaf(yk, w0.y, l[1]);
            l[2] = fmaf(yk, w0.z, l[2]); l[3] = fmaf(yk, w0.w, l[3]);
            l[4] = fmaf(yk, w1.x, l[4]); l[5] = fmaf(yk, w1.y, l[5]);
            l[6] = fmaf(yk, w1.z, l[6]); l[7] = fmaf(yk, w1.w, l[7]);
        }
#pragma unroll
        for (int j = 0; j < 8; ++j) l[j] *= 0.5f;   // stored logits are pre-scaled by 1/tau
        float sy = ((ypv[0] + ypv[1]) + (ypv[2] + ypv[3])) + ((ypv[4] + ypv[5]) + (ypv[6] + ypv[7]));
        float acc = 0.f;
#pragma unroll
        for (int j = 0; j < 8; ++j) {
            float tp = fmaf(DPS, ypv[j], OFFV * sy);
            acc = fmaf(yt[j], logf(fmaxf(tp, 1e-8f)), acc);
        }
        lp = acc;
    }
    float m = fmaxf(fmaxf(fmaxf(l[0], l[1]), fmaxf(l[2], l[3])),
                    fmaxf(fmaxf(l[4], l[5]), fmaxf(l[6], l[7])));
    float se = 0.f;
#pragma unroll
    for (int j = 0; j < 8; ++j) se += __expf(l[j] - m);
    float lse = m + logf(se);
    float lq = 0.f;
#pragma unroll
    for (int j = 0; j < 8; ++j) lq = fmaf(yt[j], l[j] - lse, lq);
    logq[tid] = lq;
    logp[tid] = lp;
}

// ---------------- Kernel F: output einsums + C broadcast (float4 stores) ----
__global__ __launch_bounds__(128) void out_kernel(
    const float* __restrict__ yseq,
    const float* __restrict__ A, const float* __restrict__ Bm,
    const float* __restrict__ C, const float* __restrict__ Q,
    float4* __restrict__ out4) {
    int bt = blockIdx.x;   // b*T + t
    __shared__ float ys[8];
    if (threadIdx.x < 8) ys[threadIdx.x] = yseq[(size_t)bt * 8 + threadIdx.x];
    __syncthreads();
    float yr[8];
#pragma unroll
    for (int k = 0; k < 8; ++k) yr[k] = ys[k];

    const float4* A4 = (const float4*)A;
    const float4* B4 = (const float4*)Bm;
    const float4* Q4 = (const float4*)Q;
    const float4* C4 = (const float4*)C;

    for (int q = threadIdx.x; q < 288; q += 128) {
        float4 v = make_float4(0.f, 0.f, 0.f, 0.f);
        size_t oidx;
        if (q < 64) {
#pragma unroll
            for (int k = 0; k < 8; ++k) {
                float4 w = A4[k * 64 + q];
                v.x = fmaf(yr[k], w.x, v.x);
                v.y = fmaf(yr[k], w.y, v.y);
                v.z = fmaf(yr[k], w.z, v.z);
                v.w = fmaf(yr[k], w.w, v.w);
            }
            oidx = (size_t)(OUT_A / 4) + (size_t)bt * 64 + q;
        } else if (q < 96) {
            int qb = q - 64;
#pragma unroll
            for (int k = 0; k < 8; ++k) {
                float4 w = B4[k * 32 + qb];
                v.x = fmaf(yr[k], w.x, v.x);
                v.y = fmaf(yr[k], w.y, v.y);
                v.z = fmaf(yr[k], w.z, v.z);
                v.w = fmaf(yr[k], w.w, v.w);
            }
            oidx = (size_t)(OUT_B / 4) + (size_t)bt * 32 + qb;
        } else if (q < 160) {
            int qq = q - 96;
#pragma unroll
            for (int k = 0; k < 8; ++k) {
                float4 w = Q4[k * 64 + qq];
                v.x = fmaf(yr[k], w.x, v.x);
                v.y = fmaf(yr[k], w.y, v.y);
                v.z = fmaf(yr[k], w.z, v.z);
                v.w = fmaf(yr[k], w.w, v.w);
            }
            oidx = (size_t)(OUT_Q / 4) + (size_t)bt * 64 + qq;
        } else {
            int qc = q - 160;
            v = C4[qc];
            oidx = (size_t)(OUT_C / 4) + (size_t)bt * 128 + qc;
        }
        out4[oidx] = v;
    }
}

extern "C" void kernel_launch(void* const* d_in, const int* in_sizes, int n_in,
                              void* d_out, int out_size, void* d_ws, size_t ws_size,
                              hipStream_t stream) {
    const float* a_seq = (const float*)d_in[0];
    const float* A     = (const float*)d_in[1];
    const float* Bmat  = (const float*)d_in[2];
    const float* C     = (const float*)d_in[3];
    const float* Q     = (const float*)d_in[4];
    const float* wih_f = (const float*)d_in[5];
    const float* whh_f = (const float*)d_in[6];
    const float* bih_f = (const float*)d_in[7];
    const float* bhh_f = (const float*)d_in[8];
    const float* wih_b = (const float*)d_in[9];
    const float* whh_b = (const float*)d_in[10];
    const float* bih_b = (const float*)d_in[11];
    const float* bhh_b = (const float*)d_in[12];
    const float* wl    = (const float*)d_in[13];
    const float* bl    = (const float*)d_in[14];
    const float* wi    = (const float*)d_in[15];
    const float* bi    = (const float*)d_in[16];
    const float* u0    = (const float*)d_in[17];
    const float* useq  = (const float*)d_in[18];

    float* ws = (float*)d_ws;
    float* gx     = ws + WS_GX;
    float* gsb    = ws + WS_GS;       // aliases gx dir=1 half (written after GRU)
    float* hseq   = ws + WS_HSEQ;
    float* logits = ws + WS_LOGITS;   // aliases gx dir=0 half (written after GRU)
    float* initl  = ws + WS_INIT;
    float* yseq   = ws + WS_YSEQ;

    float* outf = (float*)d_out;
    float* logq = outf + OUT_LQ;
    float* logp = outf + OUT_LP;

    gx_kernel<<<B * (T / 64), 192, 0, stream>>>(a_seq, wih_f, bih_f, wih_b, bih_b, gx);
    gru_kernel<<<256, 64, 0, stream>>>(gx, whh_f, bhh_f, whh_b, bhh_b, hseq);
    {
        int total = B * T * KK;
        gsc_kernel<<<(total + 255) / 256, 256, 0, stream>>>(u0, useq, gsb);
    }
    logits_kernel<<<T * B / 4, 256, 0, stream>>>(hseq, wl, bl, wi, bi, logits, initl);
    scan_kernel<<<4, 128, 0, stream>>>(logits, initl, gsb, yseq);
    lqlp_kernel<<<(B * T + 255) / 256, 256, 0, stream>>>(logits, initl, yseq, logq, logp);
    out_kernel<<<B * T, 128, 0, stream>>>(yseq, A, Bmat, C, Q, (float4*)d_out);
}

// Round 10
// 577.291 us; speedup vs baseline: 1.2319x; 1.0078x over previous
//
#include <hip/hip_runtime.h>
#include <math.h>

#define T 512
#define B 128
#define KK 8
#define HH 32
#define PP 32

// ws layout (floats)
#define WS_GX    0             /* gx [dir*B+b][t][96] = 12582912 floats */
#define WS_GS    6291456       /* alias gx dir=1 half: gumbel noise [t][b][8], written after GRU */
#define WS_HSEQ  12582912
#define WS_LOGITS 0            /* alias gx dir=0 half: scaled logits [t][b][64], written after GRU */
#define WS_INIT  16777216
#define WS_YSEQ  16778240

// d_out layout (floats)
#define OUT_A    0
#define OUT_B    16777216
#define OUT_C    25165824
#define OUT_Q    58720256
#define OUT_LQ   75497472
#define OUT_LP   75563008

#define TINV 2.0f
#define PSTAY 0.9f
#define OFFV (0.1f / 7.0f)
#define DPS (PSTAY - OFFV)
#define LOG_INV_K (-2.0794415416798357f)

typedef float f4v __attribute__((ext_vector_type(4)));
typedef __attribute__((address_space(3))) float as3f;

// async DMA global->LDS, 16B/lane, opaque to compiler (no auto waitcnt insertion)
__device__ __forceinline__ void dma16(unsigned ldsbyte, int voffbyte, const void* sbase) {
    asm volatile("s_mov_b32 m0, %0\n\t"
                 "global_load_lds_dwordx4 %1, %2"
                 :: "s"(ldsbyte), "v"(voffbyte), "s"(sbase)
                 : "memory");
}
// stores kept in asm: compiler does not track them -> no per-iter vmcnt drains
__device__ __forceinline__ void st16(void* p, f4v v) {
    asm volatile("global_store_dwordx4 %0, %1, off" :: "v"(p), "v"(v) : "memory");
}
// pinned LDS read: output lives in registers, cannot be rematerialized at use
__device__ __forceinline__ f4v ldsr16(int addr) {
    f4v out;
    asm volatile("ds_read_b128 %0, %1" : "=v"(out) : "v"(addr));
    return out;
}
// pinned global loads: outputs live in registers; caller does counted vmcnt
__device__ __forceinline__ f4v ldg16(const void* p) {
    f4v out;
    asm volatile("global_load_dwordx4 %0, %1, off" : "=v"(out) : "v"(p) : "memory");
    return out;
}
__device__ __forceinline__ float ldg4(const void* p) {
    float out;
    asm volatile("global_load_dword %0, %1, off" : "=v"(out) : "v"(p) : "memory");
    return out;
}

// ---------------- Kernel A: gx tiled: W in regs, x tile in LDS --------------
__global__ __launch_bounds__(192) void gx_kernel(
    const float* __restrict__ a_seq,
    const float* __restrict__ wih_f, const float* __restrict__ bih_f,
    const float* __restrict__ wih_b, const float* __restrict__ bih_b,
    float* __restrict__ gx) {
    __shared__ float xt[64 * 32];
    int blk = blockIdx.x;
    int b = blk >> 3;
    int t0 = (blk & 7) << 6;
    int g = threadIdx.x;            // 0..191
    int dir = (g >= 96) ? 1 : 0;
    int gg = dir ? (g - 96) : g;
    const float* w = dir ? wih_b : wih_f;
    const float* bv = dir ? bih_b : bih_f;

    {
        const float4* src = (const float4*)(a_seq + ((size_t)b * T + t0) * PP);
        float4* dst = (float4*)xt;
        for (int idx = g; idx < 512; idx += 192) dst[idx] = src[idx];
    }
    float wreg[32];
#pragma unroll
    for (int q = 0; q < 8; ++q) {
        float4 wv = *(const float4*)(w + (size_t)gg * PP + q * 4);
        wreg[q * 4 + 0] = wv.x; wreg[q * 4 + 1] = wv.y;
        wreg[q * 4 + 2] = wv.z; wreg[q * 4 + 3] = wv.w;
    }
    float bias = bv[gg];
    __syncthreads();

    float* op = gx + ((size_t)(dir * B + b) * T + t0) * 96 + gg;
#pragma unroll 4
    for (int r = 0; r < 64; ++r) {
        const float4* xr = (const float4*)(xt + r * 32);
        float acc = bias;
#pragma unroll
        for (int q = 0; q < 8; ++q) {
            float4 xv = xr[q];
            acc = fmaf(xv.x, wreg[q * 4 + 0], acc);
            acc = fmaf(xv.y, wreg[q * 4 + 1], acc);
            acc = fmaf(xv.z, wreg[q * 4 + 2], acc);
            acc = fmaf(xv.w, wreg[q * 4 + 3], acc);
        }
        op[(size_t)r * 96] = acc;
    }
}

// ---------------- Kernel B: GRU scan, all-asm VM ops, counted vmcnt ---------
// 1 wave per (dir,b) chain, 256 blocks. Weights (24 x f4v = 96 VGPR) + biases
// asm-pinned resident. gx prefetch: double-buffered 8-step groups, 24 asm
// loads/group issued 1 group (~2400 cyc) ahead; s_waitcnt vmcnt(32) before
// consuming (32 = 8 stores + 24 loads younger than the group's loads; store
// ACKs sit inside the allowance and are never waited on).
__global__ __launch_bounds__(64, 1) void gru_kernel(
    const float* __restrict__ gx,
    const float* __restrict__ whh_f, const float* __restrict__ bhh_f,
    const float* __restrict__ whh_b, const float* __restrict__ bhh_b,
    float* __restrict__ hseq) {
    int cid = blockIdx.x;            // 0..255 = dir*128 + b
    int b = cid & 127;
    int dir = cid >> 7;
    int i = threadIdx.x & 31;
    const float* whh = dir ? whh_b : whh_f;
    const float* bhh = dir ? bhh_b : bhh_f;
    const float* gp0 = gx + (size_t)cid * (T * 96);

    // asm-pinned weights + biases (27 vm loads)
    f4v wr[8], wz[8], wn[8];
#pragma unroll
    for (int q = 0; q < 8; ++q) {
        wr[q] = ldg16(whh + (size_t)i * 32 + q * 4);
        wz[q] = ldg16(whh + (size_t)(32 + i) * 32 + q * 4);
        wn[q] = ldg16(whh + (size_t)(64 + i) * 32 + q * 4);
    }
    float bhr = ldg4(bhh + i);
    float bhz = ldg4(bhh + 32 + i);
    float bhn = ldg4(bhh + 64 + i);

    const float* p = gp0 + (dir ? (T - 1) * 96 : 0);
    int gstep = dir ? -96 : 96;
    int voff = (((dir ? (T - 1) : 0) * B + b) * 64 + dir * 32 + i) * 4;
    int vstep = dir ? -(B * 64 * 4) : (B * 64 * 4);

    float pxrA[8], pxzA[8], pxnA[8], pxrB[8], pxzB[8], pxnB[8];

#define LOADG(PR, PZ, PN, G0) do {                                             \
        _Pragma("unroll")                                                      \
        for (int u_ = 0; u_ < 8; ++u_) {                                       \
            int sc_ = (G0) * 8 + u_; if (sc_ > T - 1) sc_ = T - 1;             \
            const float* rp_ = p + sc_ * gstep;                                \
            PR[u_] = ldg4(rp_ + i);                                            \
            PZ[u_] = ldg4(rp_ + 32 + i);                                       \
            PN[u_] = ldg4(rp_ + 64 + i);                                       \
        }                                                                      \
    } while (0)

#define GWAIT(N) do {                                                          \
        asm volatile("s_waitcnt vmcnt(" #N ")" ::: "memory");                  \
        __builtin_amdgcn_sched_barrier(0);                                     \
    } while (0)

#define GSTEP(PR, PZ, PN, SLOT) do {                                           \
        float hr_ = PR[SLOT] + bhr;                                            \
        float hz_ = PZ[SLOT] + bhz;                                            \
        float hn_ = bhn;                                                       \
        _Pragma("unroll")                                                      \
        for (int q_ = 0; q_ < 8; ++q_) {                                       \
            _Pragma("unroll")                                                  \
            for (int c_ = 0; c_ < 4; ++c_) {                                   \
                float hj_ = __uint_as_float(                                   \
                    __builtin_amdgcn_readlane(__float_as_uint(h), q_ * 4 + c_)); \
                hr_ = fmaf(wr[q_][c_], hj_, hr_);                              \
                hz_ = fmaf(wz[q_][c_], hj_, hz_);                              \
                hn_ = fmaf(wn[q_][c_], hj_, hn_);                              \
            }                                                                  \
        }                                                                      \
        float r_ = __builtin_amdgcn_rcpf(1.f + __expf(-hr_));                  \
        float z_ = __builtin_amdgcn_rcpf(1.f + __expf(-hz_));                  \
        float na_ = fmaf(r_, hn_, PN[SLOT]);                                   \
        float e2_ = __expf(-2.f * fabsf(na_));                                 \
        float n_ = copysignf((1.f - e2_) * __builtin_amdgcn_rcpf(1.f + e2_), na_); \
        h = fmaf(z_, h - n_, n_);                                              \
        asm volatile("global_store_dword %0, %1, %2"                           \
                     :: "v"(voff), "v"(h), "s"(hseq) : "memory");              \
        voff += vstep;                                                         \
    } while (0)

    // prologue: group 0 into A (24 loads). Wait all 27+24 setup/첫 loads done.
    LOADG(pxrA, pxzA, pxnA, 0);
    GWAIT(0);
    float h = 0.f;

    // 64 groups of 8 steps; unroll-2 for A/B double buffer.
    for (int gq = 0; gq < 32; ++gq) {
        LOADG(pxrB, pxzB, pxnB, 2 * gq + 1);          // prefetch next group
        GWAIT(32);                                     // group A's loads landed
        GSTEP(pxrA, pxzA, pxnA, 0); GSTEP(pxrA, pxzA, pxnA, 1);
        GSTEP(pxrA, pxzA, pxnA, 2); GSTEP(pxrA, pxzA, pxnA, 3);
        GSTEP(pxrA, pxzA, pxnA, 4); GSTEP(pxrA, pxzA, pxnA, 5);
        GSTEP(pxrA, pxzA, pxnA, 6); GSTEP(pxrA, pxzA, pxnA, 7);
        LOADG(pxrA, pxzA, pxnA, 2 * gq + 2);
        GWAIT(32);                                     // group B's loads landed
        GSTEP(pxrB, pxzB, pxnB, 0); GSTEP(pxrB, pxzB, pxnB, 1);
        GSTEP(pxrB, pxzB, pxnB, 2); GSTEP(pxrB, pxzB, pxnB, 3);
        GSTEP(pxrB, pxzB, pxnB, 4); GSTEP(pxrB, pxzB, pxnB, 5);
        GSTEP(pxrB, pxzB, pxnB, 6); GSTEP(pxrB, pxzB, pxnB, 7);
    }
#undef LOADG
#undef GWAIT
#undef GSTEP
}

// ---------------- Kernel C: logits' = (h_seq @ wl^T + bl) * (1/tau) ---------
__global__ __launch_bounds__(256) void logits_kernel(
    const float* __restrict__ hseq,
    const float* __restrict__ wl, const float* __restrict__ bl,
    const float* __restrict__ wi, const float* __restrict__ bi,
    float* __restrict__ logits, float* __restrict__ initl) {
    int q = threadIdx.x >> 6;
    int tb = blockIdx.x * 4 + q;   // t*B + b
    int g = threadIdx.x & 63;
    __shared__ float hrow[4][64];
    hrow[q][g] = hseq[(size_t)tb * 64 + g];
    __syncthreads();
    float acc = bl[g];
    const float* wrow = wl + (size_t)g * 64;
#pragma unroll
    for (int c = 0; c < 64; ++c) acc = fmaf(wrow[c], hrow[q][c], acc);
    logits[(size_t)tb * 64 + g] = acc * TINV;
    if (tb < B && g < 8) {            // t == 0 blocks, tb == b
        float a2 = bi[g];
        const float* w2 = wi + (size_t)g * 64;
#pragma unroll
        for (int c = 0; c < 64; ++c) a2 = fmaf(w2[c], hrow[q][c], a2);
        initl[tb * 8 + g] = a2;
    }
}

// ---------------- Kernel G: gumbel noise [t][b][8], pre-scaled by 1/tau -----
__global__ __launch_bounds__(256) void gsc_kernel(
    const float* __restrict__ u0, const float* __restrict__ useq,
    float* __restrict__ gs) {
    int id = blockIdx.x * 256 + threadIdx.x;
    if (id >= T * B * KK) return;
    int j = id & 7;
    int b = (id >> 3) & 127;
    int t = id >> 10;
    float u = (t == 0) ? u0[b * 8 + j]
                       : useq[((size_t)b * (T - 1) + (t - 1)) * 8 + j];
    gs[id] = -logf(-logf(u)) * TINV;   // precise logf: u near 1 is ill-conditioned
}

// ---------------- Kernel D: y-only scan, producer/consumer wave split -------
// (unchanged from round 9 — known-good at 183 us)
__global__ __launch_bounds__(128, 1) void scan_kernel(
    const float* __restrict__ logits, const float* __restrict__ initl,
    const float* __restrict__ gs, float* __restrict__ yseq) {
    __shared__ float lds[6][2304];   // 6 slots x (32*64 logits + 32*8 gs)
    int tid = threadIdx.x;
    int wave = tid >> 6;
    int r = tid & 63;
    int b0 = blockIdx.x * 32;
    int b = b0 + (r & 31);
    int k15 = r & 15;

    unsigned ldsU = (unsigned)(unsigned long long)(as3f*)(&lds[0][0]);

#define ISSUE(tt, sl) do {                                                   \
        unsigned lb_ = ldsU + (unsigned)((sl) * 9216);                       \
        const char* bt_ = (const char*)logits + (size_t)(tt) * 32768;        \
        const char* gt_ = (const char*)gs + (size_t)(tt) * 4096;             \
        dma16(lb_ + 0 * 1024u, lof[0], bt_);                                 \
        dma16(lb_ + 1 * 1024u, lof[1], bt_);                                 \
        dma16(lb_ + 2 * 1024u, lof[2], bt_);                                 \
        dma16(lb_ + 3 * 1024u, lof[3], bt_);                                 \
        dma16(lb_ + 4 * 1024u, lof[4], bt_);                                 \
        dma16(lb_ + 5 * 1024u, lof[5], bt_);                                 \
        dma16(lb_ + 6 * 1024u, lof[6], bt_);                                 \
        dma16(lb_ + 7 * 1024u, lof[7], bt_);                                 \
        dma16(lb_ + 8192u, gof, gt_);                                        \
    } while (0)

    if (wave == 1) {
        // ---------------- DMA producer wave ----------------
        int lof[8];
#pragma unroll
        for (int q = 0; q < 8; ++q) {
            int rr = q * 4 + (r >> 4);         // tile row 0..31
            int cc = r & 15;                   // linear f4v col in LDS
            lof[q] = (((b0 + rr) * 64) + ((cc ^ (rr & 15)) << 2)) << 2;
        }
        int gof;
        {
            int rg = r >> 1;
            int cc = r & 1;
            gof = (((b0 + rg) * 8) + ((cc ^ (rg & 1)) << 2)) << 2;
        }
#pragma unroll
        for (int p = 1; p <= 5; ++p) ISSUE(p, p);
        asm volatile("s_waitcnt vmcnt(36)" ::: "memory");   // slot 1 landed
        __builtin_amdgcn_s_barrier();                        // #0
        for (int t = 1; t < T; ++t) {
            asm volatile("s_waitcnt vmcnt(27)" ::: "memory"); // slot t+1 landed
            __builtin_amdgcn_s_barrier();                     // #t
            int tp = t + 5; if (tp > T - 1) tp = T - 1;
            ISSUE(tp, (t + 5) % 6);
        }
        return;
    }

    // ---------------- compute consumer wave ----------------
    unsigned rbase = ldsU + (unsigned)((r & 31) * 256);
    unsigned gbase = ldsU + 8192u + (unsigned)((r & 31) * 32);

#define SREAD(LL, GA, GB, tt) do {                                           \
        int so_ = ((tt) % 6) * 9216;                                         \
        _Pragma("unroll")                                                    \
        for (int m_ = 0; m_ < 16; ++m_)                                      \
            LL[m_] = ldsr16((int)(rbase + so_ + ((m_ ^ k15) << 4)));         \
        GA = ldsr16((int)(gbase + so_ + ((r & 1) << 4)));                    \
        GB = ldsr16((int)(gbase + so_ + (((r & 1) ^ 1) << 4)));              \
    } while (0)

#define LWAIT() do {                                                         \
        asm volatile("s_waitcnt lgkmcnt(0)" ::: "memory");                   \
        __builtin_amdgcn_sched_barrier(0);                                   \
    } while (0)

#define SCOMP(LL, GA, GB, tt) do {                                           \
        float pl_[8];                                                        \
        _Pragma("unroll")                                                    \
        for (int j_ = 0; j_ < 8; ++j_) pl_[j_] = 0.f;                        \
        _Pragma("unroll")                                                    \
        for (int k_ = 0; k_ < 8; ++k_) {                                     \
            f4v w0_ = LL[2 * k_], w1_ = LL[2 * k_ + 1];                      \
            float ek_ = e[k_];                                               \
            pl_[0] = fmaf(ek_, w0_.x, pl_[0]); pl_[1] = fmaf(ek_, w0_.y, pl_[1]); \
            pl_[2] = fmaf(ek_, w0_.z, pl_[2]); pl_[3] = fmaf(ek_, w0_.w, pl_[3]); \
            pl_[4] = fmaf(ek_, w1_.x, pl_[4]); pl_[5] = fmaf(ek_, w1_.y, pl_[5]); \
            pl_[6] = fmaf(ek_, w1_.z, pl_[6]); pl_[7] = fmaf(ek_, w1_.w, pl_[7]); \
        }                                                                    \
        float gg_[8] = {GA.x, GA.y, GA.z, GA.w, GB.x, GB.y, GB.z, GB.w};     \
        float ss_ = 0.f;                                                     \
        _Pragma("unroll")                                                    \
        for (int j_ = 0; j_ < 8; ++j_) {                                     \
            float a_ = fmaf(pl_[j_], sinv, gg_[j_]);                         \
            e[j_] = __expf(a_);                                              \
            ss_ += e[j_];                                                    \
        }                                                                    \
        sinv = __builtin_amdgcn_rcpf(ss_);                                   \
        if (r < 32) {                                                        \
            f4v v0_ = (f4v){e[0] * sinv, e[1] * sinv, e[2] * sinv, e[3] * sinv}; \
            f4v v1_ = (f4v){e[4] * sinv, e[5] * sinv, e[6] * sinv, e[7] * sinv}; \
            st16(&yp[2 * (tt)], v0_);                                        \
            st16(&yp[2 * (tt) + 1], v1_);                                    \
        }                                                                    \
    } while (0)

    f4v* yp = (f4v*)(yseq + (size_t)b * T * 8);
    float e[8];
    float sinv;

    // ---- t = 0 from initl + gs[0] (plain loads, compiler-tracked) ----
    {
        const f4v* il4 = (const f4v*)(initl + b * 8);
        f4v i0 = il4[0], i1 = il4[1];
        const f4v* g4 = (const f4v*)(gs + b * 8);
        f4v G0 = g4[0], G1 = g4[1];
        float a[8];
        a[0] = fmaf(i0.x, TINV, G0.x); a[1] = fmaf(i0.y, TINV, G0.y);
        a[2] = fmaf(i0.z, TINV, G0.z); a[3] = fmaf(i0.w, TINV, G0.w);
        a[4] = fmaf(i1.x, TINV, G1.x); a[5] = fmaf(i1.y, TINV, G1.y);
        a[6] = fmaf(i1.z, TINV, G1.z); a[7] = fmaf(i1.w, TINV, G1.w);
        float ssum = 0.f;
#pragma unroll
        for (int j = 0; j < 8; ++j) { e[j] = __expf(a[j]); ssum += e[j]; }
        sinv = __builtin_amdgcn_rcpf(ssum);
        if (r < 32) {
            f4v y0v = (f4v){e[0] * sinv, e[1] * sinv, e[2] * sinv, e[3] * sinv};
            f4v y1v = (f4v){e[4] * sinv, e[5] * sinv, e[6] * sinv, e[7] * sinv};
            st16(&yp[0], y0v);
            st16(&yp[1], y1v);
        }
    }

    f4v LA[16], LB[16], gaA, gbA, gaB, gbB;

    __builtin_amdgcn_s_barrier();      // #0: slot 1 landed (producer vmcnt(36))
    SREAD(LA, gaA, gbA, 1);

    for (int t = 1; t < T - 1; t += 2) {
        __builtin_amdgcn_s_barrier();  // #t: slot t+1 landed
        LWAIT();                       // prior phase's SREAD retired
        SREAD(LB, gaB, gbB, t + 1);
        SCOMP(LA, gaA, gbA, t);

        __builtin_amdgcn_s_barrier();  // #t+1: slot t+2 landed
        LWAIT();
        SREAD(LA, gaA, gbA, t + 2);
        SCOMP(LB, gaB, gbB, t + 1);
    }
    __builtin_amdgcn_s_barrier();      // #511
    LWAIT();
    SCOMP(LA, gaA, gbA, T - 1);
#undef ISSUE
#undef SREAD
#undef LWAIT
#undef SCOMP
}

// ---------------- Kernel E: parallel log_q / log_p --------------------------
__global__ __launch_bounds__(256) void lqlp_kernel(
    const float* __restrict__ logits, const float* __restrict__ initl,
    const float* __restrict__ yseq,
    float* __restrict__ logq, float* __restrict__ logp) {
    int tid = blockIdx.x * 256 + threadIdx.x;   // tid = b*T + t
    if (tid >= B * T) return;
    int b = tid >> 9;
    int t = tid & (T - 1);

    const float4* yt4 = (const float4*)(yseq + (size_t)tid * 8);
    float4 y0 = yt4[0], y1 = yt4[1];
    float yt[8] = {y0.x, y0.y, y0.z, y0.w, y1.x, y1.y, y1.z, y1.w};

    float l[8];
    float lp;
    if (t == 0) {
        const float4* il4 = (const float4*)(initl + b * 8);
        float4 i0 = il4[0], i1 = il4[1];
        l[0] = i0.x; l[1] = i0.y; l[2] = i0.z; l[3] = i0.w;
        l[4] = i1.x; l[5] = i1.y; l[6] = i1.z; l[7] = i1.w;
        float sy = ((yt[0] + yt[1]) + (yt[2] + yt[3])) + ((yt[4] + yt[5]) + (yt[6] + yt[7]));
        lp = LOG_INV_K * sy;
    } else {
        const float4* yp4 = (const float4*)(yseq + (size_t)tid * 8 - 8);
        float4 p0 = yp4[0], p1 = yp4[1];
        float ypv[8] = {p0.x, p0.y, p0.z, p0.w, p1.x, p1.y, p1.z, p1.w};
        const float4* L4 = (const float4*)(logits + ((size_t)t * B + b) * 64);
#pragma unroll
        for (int j = 0; j < 8; ++j) l[j] = 0.f;
#pragma unroll
        for (int k = 0; k < 8; ++k) {
            float4 w0 = L4[2 * k], w1 = L4[2 * k + 1];
            float yk = ypv[k];
            l[0] = fmaf(yk, w0.x, l[0]); l[1] = fmaf(yk, w0.y, l[1]);
            l[2] = fmaf(yk, w0.z, l[2]); l[3] = fmaf(yk, w0.w, l[3]);
            l[4] = fmaf(yk, w1.x, l[4]); l[5] = fmaf(yk, w1.y, l[5]);
            l[6] = fmaf(yk, w1.z, l[6]); l[7] = fmaf(yk, w1.w, l[7]);
        }
#pragma unroll
        for (int j = 0; j < 8; ++j) l[j] *= 0.5f;   // stored logits are pre-scaled by 1/tau
        float sy = ((ypv[0] + ypv[1]) + (ypv[2] + ypv[3])) + ((ypv[4] + ypv[5]) + (ypv[6] + ypv[7]));
        float acc = 0.f;
#pragma unroll
        for (int j = 0; j < 8; ++j) {
            float tp = fmaf(DPS, ypv[j], OFFV * sy);
            acc = fmaf(yt[j], logf(fmaxf(tp, 1e-8f)), acc);
        }
        lp = acc;
    }
    float m = fmaxf(fmaxf(fmaxf(l[0], l[1]), fmaxf(l[2], l[3])),
                    fmaxf(fmaxf(l[4], l[5]), fmaxf(l[6], l[7])));
    float se = 0.f;
#pragma unroll
    for (int j = 0; j < 8; ++j) se += __expf(l[j] - m);
    float lse = m + logf(se);
    float lq = 0.f;
#pragma unroll
    for (int j = 0; j < 8; ++j) lq = fmaf(yt[j], l[j] - lse, lq);
    logq[tid] = lq;
    logp[tid] = lp;
}

// ---------------- Kernel F: output einsums + C broadcast (float4 stores) ----
__global__ __launch_bounds__(128) void out_kernel(
    const float* __restrict__ yseq,
    const float* __restrict__ A, const float* __restrict__ Bm,
    const float* __restrict__ C, const float* __restrict__ Q,
    float4* __restrict__ out4) {
    int bt = blockIdx.x;   // b*T + t
    __shared__ float ys[8];
    if (threadIdx.x < 8) ys[threadIdx.x] = yseq[(size_t)bt * 8 + threadIdx.x];
    __syncthreads();
    float yr[8];
#pragma unroll
    for (int k = 0; k < 8; ++k) yr[k] = ys[k];

    const float4* A4 = (const float4*)A;
    const float4* B4 = (const float4*)Bm;
    const float4* Q4 = (const float4*)Q;
    const float4* C4 = (const float4*)C;

    for (int q = threadIdx.x; q < 288; q += 128) {
        float4 v = make_float4(0.f, 0.f, 0.f, 0.f);
        size_t oidx;
        if (q < 64) {
#pragma unroll
            for (int k = 0; k < 8; ++k) {
                float4 w = A4[k * 64 + q];
                v.x = fmaf(yr[k], w.x, v.x);
                v.y = fmaf(yr[k], w.y, v.y);
                v.z = fmaf(yr[k], w.z, v.z);
                v.w = fmaf(yr[k], w.w, v.w);
            }
            oidx = (size_t)(OUT_A / 4) + (size_t)bt * 64 + q;
        } else if (q < 96) {
            int qb = q - 64;
#pragma unroll
            for (int k = 0; k < 8; ++k) {
                float4 w = B4[k * 32 + qb];
                v.x = fmaf(yr[k], w.x, v.x);
                v.y = fmaf(yr[k], w.y, v.y);
                v.z = fmaf(yr[k], w.z, v.z);
                v.w = fmaf(yr[k], w.w, v.w);
            }
            oidx = (size_t)(OUT_B / 4) + (size_t)bt * 32 + qb;
        } else if (q < 160) {
            int qq = q - 96;
#pragma unroll
            for (int k = 0; k < 8; ++k) {
                float4 w = Q4[k * 64 + qq];
                v.x = fmaf(yr[k], w.x, v.x);
                v.y = fmaf(yr[k], w.y, v.y);
                v.z = fmaf(yr[k], w.z, v.z);
                v.w = fmaf(yr[k], w.w, v.w);
            }
            oidx = (size_t)(OUT_Q / 4) + (size_t)bt * 64 + qq;
        } else {
            int qc = q - 160;
            v = C4[qc];
            oidx = (size_t)(OUT_C / 4) + (size_t)bt * 128 + qc;
        }
        out4[oidx] = v;
    }
}

extern "C" void kernel_launch(void* const* d_in, const int* in_sizes, int n_in,
                              void* d_out, int out_size, void* d_ws, size_t ws_size,
                              hipStream_t stream) {
    const float* a_seq = (const float*)d_in[0];
    const float* A     = (const float*)d_in[1];
    const float* Bmat  = (const float*)d_in[2];
    const float* C     = (const float*)d_in[3];
    const float* Q     = (const float*)d_in[4];
    const float* wih_f = (const float*)d_in[5];
    const float* whh_f = (const float*)d_in[6];
    const float* bih_f = (const float*)d_in[7];
    const float* bhh_f = (const float*)d_in[8];
    const float* wih_b = (const float*)d_in[9];
    const float* whh_b = (const float*)d_in[10];
    const float* bih_b = (const float*)d_in[11];
    const float* bhh_b = (const float*)d_in[12];
    const float* wl    = (const float*)d_in[13];
    const float* bl    = (const float*)d_in[14];
    const float* wi    = (const float*)d_in[15];
    const float* bi    = (const float*)d_in[16];
    const float* u0    = (const float*)d_in[17];
    const float* useq  = (const float*)d_in[18];

    float* ws = (float*)d_ws;
    float* gx     = ws + WS_GX;
    float* gsb    = ws + WS_GS;       // aliases gx dir=1 half (written after GRU)
    float* hseq   = ws + WS_HSEQ;
    float* logits = ws + WS_LOGITS;   // aliases gx dir=0 half (written after GRU)
    float* initl  = ws + WS_INIT;
    float* yseq   = ws + WS_YSEQ;

    float* outf = (float*)d_out;
    float* logq = outf + OUT_LQ;
    float* logp = outf + OUT_LP;

    gx_kernel<<<B * (T / 64), 192, 0, stream>>>(a_seq, wih_f, bih_f, wih_b, bih_b, gx);
    gru_kernel<<<256, 64, 0, stream>>>(gx, whh_f, bhh_f, whh_b, bhh_b, hseq);
    {
        int total = B * T * KK;
        gsc_kernel<<<(total + 255) / 256, 256, 0, stream>>>(u0, useq, gsb);
    }
    logits_kernel<<<T * B / 4, 256, 0, stream>>>(hseq, wl, bl, wi, bi, logits, initl);
    scan_kernel<<<4, 128, 0, stream>>>(logits, initl, gsb, yseq);
    lqlp_kernel<<<(B * T + 255) / 256, 256, 0, stream>>>(logits, initl, yseq, logq, logp);
    out_kernel<<<B * T, 128, 0, stream>>>(yseq, A, Bmat, C, Q, (float4*)d_out);
}

// Round 11
// 570.516 us; speedup vs baseline: 1.2466x; 1.0119x over previous
//
#include <hip/hip_runtime.h>
#include <math.h>

#define T 512
#define B 128
#define KK 8
#define HH 32
#define PP 32

// ws layout (floats)
#define WS_GX    0             /* gx [dir*B+b][t][96] = 12582912 floats */
#define WS_GS    6291456       /* alias gx dir=1 half: gumbel noise [t][b][8], written after GRU */
#define WS_HSEQ  12582912
#define WS_LOGITS 0            /* alias gx dir=0 half: scaled logits [t][b][64], written after GRU */
#define WS_INIT  16777216
#define WS_YSEQ  16778240

// d_out layout (floats)
#define OUT_A    0
#define OUT_B    16777216
#define OUT_C    25165824
#define OUT_Q    58720256
#define OUT_LQ   75497472
#define OUT_LP   75563008

#define TINV 2.0f
#define PSTAY 0.9f
#define OFFV (0.1f / 7.0f)
#define DPS (PSTAY - OFFV)
#define LOG_INV_K (-2.0794415416798357f)

typedef float f4v __attribute__((ext_vector_type(4)));
typedef __attribute__((address_space(3))) float as3f;

// async DMA global->LDS, 16B/lane, opaque to compiler (no auto waitcnt insertion)
__device__ __forceinline__ void dma16(unsigned ldsbyte, int voffbyte, const void* sbase) {
    asm volatile("s_mov_b32 m0, %0\n\t"
                 "global_load_lds_dwordx4 %1, %2"
                 :: "s"(ldsbyte), "v"(voffbyte), "s"(sbase)
                 : "memory");
}
// stores kept in asm: compiler does not track them -> no per-iter vmcnt drains
__device__ __forceinline__ void st16(void* p, f4v v) {
    asm volatile("global_store_dwordx4 %0, %1, off" :: "v"(p), "v"(v) : "memory");
}
// pinned LDS read: output lives in registers, cannot be rematerialized at use
__device__ __forceinline__ f4v ldsr16(int addr) {
    f4v out;
    asm volatile("ds_read_b128 %0, %1" : "=v"(out) : "v"(addr));
    return out;
}
// pinned global loads: outputs live in registers; caller does counted vmcnt
__device__ __forceinline__ f4v ldg16(const void* p) {
    f4v out;
    asm volatile("global_load_dwordx4 %0, %1, off" : "=v"(out) : "v"(p) : "memory");
    return out;
}
__device__ __forceinline__ float ldg4(const void* p) {
    float out;
    asm volatile("global_load_dword %0, %1, off" : "=v"(out) : "v"(p) : "memory");
    return out;
}

// ---------------- Kernel A: gx tiled: W in regs, x tile in LDS --------------
__global__ __launch_bounds__(192) void gx_kernel(
    const float* __restrict__ a_seq,
    const float* __restrict__ wih_f, const float* __restrict__ bih_f,
    const float* __restrict__ wih_b, const float* __restrict__ bih_b,
    float* __restrict__ gx) {
    __shared__ float xt[64 * 32];
    int blk = blockIdx.x;
    int b = blk >> 3;
    int t0 = (blk & 7) << 6;
    int g = threadIdx.x;            // 0..191
    int dir = (g >= 96) ? 1 : 0;
    int gg = dir ? (g - 96) : g;
    const float* w = dir ? wih_b : wih_f;
    const float* bv = dir ? bih_b : bih_f;

    {
        const float4* src = (const float4*)(a_seq + ((size_t)b * T + t0) * PP);
        float4* dst = (float4*)xt;
        for (int idx = g; idx < 512; idx += 192) dst[idx] = src[idx];
    }
    float wreg[32];
#pragma unroll
    for (int q = 0; q < 8; ++q) {
        float4 wv = *(const float4*)(w + (size_t)gg * PP + q * 4);
        wreg[q * 4 + 0] = wv.x; wreg[q * 4 + 1] = wv.y;
        wreg[q * 4 + 2] = wv.z; wreg[q * 4 + 3] = wv.w;
    }
    float bias = bv[gg];
    __syncthreads();

    float* op = gx + ((size_t)(dir * B + b) * T + t0) * 96 + gg;
#pragma unroll 4
    for (int r = 0; r < 64; ++r) {
        const float4* xr = (const float4*)(xt + r * 32);
        float acc = bias;
#pragma unroll
        for (int q = 0; q < 8; ++q) {
            float4 xv = xr[q];
            acc = fmaf(xv.x, wreg[q * 4 + 0], acc);
            acc = fmaf(xv.y, wreg[q * 4 + 1], acc);
            acc = fmaf(xv.z, wreg[q * 4 + 2], acc);
            acc = fmaf(xv.w, wreg[q * 4 + 3], acc);
        }
        op[(size_t)r * 96] = acc;
    }
}

// ---------------- Kernel B: GRU scan, all-asm VM ops, counted vmcnt ---------
__global__ __launch_bounds__(64, 1) void gru_kernel(
    const float* __restrict__ gx,
    const float* __restrict__ whh_f, const float* __restrict__ bhh_f,
    const float* __restrict__ whh_b, const float* __restrict__ bhh_b,
    float* __restrict__ hseq) {
    int cid = blockIdx.x;            // 0..255 = dir*128 + b
    int b = cid & 127;
    int dir = cid >> 7;
    int i = threadIdx.x & 31;
    const float* whh = dir ? whh_b : whh_f;
    const float* bhh = dir ? bhh_b : bhh_f;
    const float* gp0 = gx + (size_t)cid * (T * 96);

    // asm-pinned weights + biases (27 vm loads)
    f4v wr[8], wz[8], wn[8];
#pragma unroll
    for (int q = 0; q < 8; ++q) {
        wr[q] = ldg16(whh + (size_t)i * 32 + q * 4);
        wz[q] = ldg16(whh + (size_t)(32 + i) * 32 + q * 4);
        wn[q] = ldg16(whh + (size_t)(64 + i) * 32 + q * 4);
    }
    float bhr = ldg4(bhh + i);
    float bhz = ldg4(bhh + 32 + i);
    float bhn = ldg4(bhh + 64 + i);

    const float* p = gp0 + (dir ? (T - 1) * 96 : 0);
    int gstep = dir ? -96 : 96;
    int voff = (((dir ? (T - 1) : 0) * B + b) * 64 + dir * 32 + i) * 4;
    int vstep = dir ? -(B * 64 * 4) : (B * 64 * 4);

    float pxrA[8], pxzA[8], pxnA[8], pxrB[8], pxzB[8], pxnB[8];

#define LOADG(PR, PZ, PN, G0) do {                                             \
        _Pragma("unroll")                                                      \
        for (int u_ = 0; u_ < 8; ++u_) {                                       \
            int sc_ = (G0) * 8 + u_; if (sc_ > T - 1) sc_ = T - 1;             \
            const float* rp_ = p + sc_ * gstep;                                \
            PR[u_] = ldg4(rp_ + i);                                            \
            PZ[u_] = ldg4(rp_ + 32 + i);                                       \
            PN[u_] = ldg4(rp_ + 64 + i);                                       \
        }                                                                      \
    } while (0)

#define GWAIT(N) do {                                                          \
        asm volatile("s_waitcnt vmcnt(" #N ")" ::: "memory");                  \
        __builtin_amdgcn_sched_barrier(0);                                     \
    } while (0)

#define GSTEP(PR, PZ, PN, SLOT) do {                                           \
        float hr_ = PR[SLOT] + bhr;                                            \
        float hz_ = PZ[SLOT] + bhz;                                            \
        float hn_ = bhn;                                                       \
        _Pragma("unroll")                                                      \
        for (int q_ = 0; q_ < 8; ++q_) {                                       \
            _Pragma("unroll")                                                  \
            for (int c_ = 0; c_ < 4; ++c_) {                                   \
                float hj_ = __uint_as_float(                                   \
                    __builtin_amdgcn_readlane(__float_as_uint(h), q_ * 4 + c_)); \
                hr_ = fmaf(wr[q_][c_], hj_, hr_);                              \
                hz_ = fmaf(wz[q_][c_], hj_, hz_);                              \
                hn_ = fmaf(wn[q_][c_], hj_, hn_);                              \
            }                                                                  \
        }                                                                      \
        float r_ = __builtin_amdgcn_rcpf(1.f + __expf(-hr_));                  \
        float z_ = __builtin_amdgcn_rcpf(1.f + __expf(-hz_));                  \
        float na_ = fmaf(r_, hn_, PN[SLOT]);                                   \
        float e2_ = __expf(-2.f * fabsf(na_));                                 \
        float n_ = copysignf((1.f - e2_) * __builtin_amdgcn_rcpf(1.f + e2_), na_); \
        h = fmaf(z_, h - n_, n_);                                              \
        asm volatile("global_store_dword %0, %1, %2"                           \
                     :: "v"(voff), "v"(h), "s"(hseq) : "memory");              \
        voff += vstep;                                                         \
    } while (0)

    LOADG(pxrA, pxzA, pxnA, 0);
    GWAIT(0);
    float h = 0.f;

    for (int gq = 0; gq < 32; ++gq) {
        LOADG(pxrB, pxzB, pxnB, 2 * gq + 1);          // prefetch next group
        GWAIT(32);                                     // group A's loads landed
        GSTEP(pxrA, pxzA, pxnA, 0); GSTEP(pxrA, pxzA, pxnA, 1);
        GSTEP(pxrA, pxzA, pxnA, 2); GSTEP(pxrA, pxzA, pxnA, 3);
        GSTEP(pxrA, pxzA, pxnA, 4); GSTEP(pxrA, pxzA, pxnA, 5);
        GSTEP(pxrA, pxzA, pxnA, 6); GSTEP(pxrA, pxzA, pxnA, 7);
        LOADG(pxrA, pxzA, pxnA, 2 * gq + 2);
        GWAIT(32);                                     // group B's loads landed
        GSTEP(pxrB, pxzB, pxnB, 0); GSTEP(pxrB, pxzB, pxnB, 1);
        GSTEP(pxrB, pxzB, pxnB, 2); GSTEP(pxrB, pxzB, pxnB, 3);
        GSTEP(pxrB, pxzB, pxnB, 4); GSTEP(pxrB, pxzB, pxnB, 5);
        GSTEP(pxrB, pxzB, pxnB, 6); GSTEP(pxrB, pxzB, pxnB, 7);
    }
#undef LOADG
#undef GWAIT
#undef GSTEP
}

// ---------------- Kernel C: logits' = (h_seq @ wl^T + bl) * (1/tau) ---------
__global__ __launch_bounds__(256) void logits_kernel(
    const float* __restrict__ hseq,
    const float* __restrict__ wl, const float* __restrict__ bl,
    const float* __restrict__ wi, const float* __restrict__ bi,
    float* __restrict__ logits, float* __restrict__ initl) {
    int q = threadIdx.x >> 6;
    int tb = blockIdx.x * 4 + q;   // t*B + b
    int g = threadIdx.x & 63;
    __shared__ float hrow[4][64];
    hrow[q][g] = hseq[(size_t)tb * 64 + g];
    __syncthreads();
    float acc = bl[g];
    const float* wrow = wl + (size_t)g * 64;
#pragma unroll
    for (int c = 0; c < 64; ++c) acc = fmaf(wrow[c], hrow[q][c], acc);
    logits[(size_t)tb * 64 + g] = acc * TINV;
    if (tb < B && g < 8) {            // t == 0 blocks, tb == b
        float a2 = bi[g];
        const float* w2 = wi + (size_t)g * 64;
#pragma unroll
        for (int c = 0; c < 64; ++c) a2 = fmaf(w2[c], hrow[q][c], a2);
        initl[tb * 8 + g] = a2;
    }
}

// ---------------- Kernel G: gumbel noise [t][b][8], pre-scaled by 1/tau -----
__global__ __launch_bounds__(256) void gsc_kernel(
    const float* __restrict__ u0, const float* __restrict__ useq,
    float* __restrict__ gs) {
    int id = blockIdx.x * 256 + threadIdx.x;
    if (id >= T * B * KK) return;
    int j = id & 7;
    int b = (id >> 3) & 127;
    int t = id >> 10;
    float u = (t == 0) ? u0[b * 8 + j]
                       : useq[((size_t)b * (T - 1) + (t - 1)) * 8 + j];
    gs[id] = -logf(-logf(u)) * TINV;   // precise logf: u near 1 is ill-conditioned
}

// ---------------- Kernel D: y-only scan, producer/consumer wave split -------
// (unchanged from round 9 — known-good at 183 us)
__global__ __launch_bounds__(128, 1) void scan_kernel(
    const float* __restrict__ logits, const float* __restrict__ initl,
    const float* __restrict__ gs, float* __restrict__ yseq) {
    __shared__ float lds[6][2304];   // 6 slots x (32*64 logits + 32*8 gs)
    int tid = threadIdx.x;
    int wave = tid >> 6;
    int r = tid & 63;
    int b0 = blockIdx.x * 32;
    int b = b0 + (r & 31);
    int k15 = r & 15;

    unsigned ldsU = (unsigned)(unsigned long long)(as3f*)(&lds[0][0]);

#define ISSUE(tt, sl) do {                                                   \
        unsigned lb_ = ldsU + (unsigned)((sl) * 9216);                       \
        const char* bt_ = (const char*)logits + (size_t)(tt) * 32768;        \
        const char* gt_ = (const char*)gs + (size_t)(tt) * 4096;             \
        dma16(lb_ + 0 * 1024u, lof[0], bt_);                                 \
        dma16(lb_ + 1 * 1024u, lof[1], bt_);                                 \
        dma16(lb_ + 2 * 1024u, lof[2], bt_);                                 \
        dma16(lb_ + 3 * 1024u, lof[3], bt_);                                 \
        dma16(lb_ + 4 * 1024u, lof[4], bt_);                                 \
        dma16(lb_ + 5 * 1024u, lof[5], bt_);                                 \
        dma16(lb_ + 6 * 1024u, lof[6], bt_);                                 \
        dma16(lb_ + 7 * 1024u, lof[7], bt_);                                 \
        dma16(lb_ + 8192u, gof, gt_);                                        \
    } while (0)

    if (wave == 1) {
        // ---------------- DMA producer wave ----------------
        int lof[8];
#pragma unroll
        for (int q = 0; q < 8; ++q) {
            int rr = q * 4 + (r >> 4);         // tile row 0..31
            int cc = r & 15;                   // linear f4v col in LDS
            lof[q] = (((b0 + rr) * 64) + ((cc ^ (rr & 15)) << 2)) << 2;
        }
        int gof;
        {
            int rg = r >> 1;
            int cc = r & 1;
            gof = (((b0 + rg) * 8) + ((cc ^ (rg & 1)) << 2)) << 2;
        }
#pragma unroll
        for (int p = 1; p <= 5; ++p) ISSUE(p, p);
        asm volatile("s_waitcnt vmcnt(36)" ::: "memory");   // slot 1 landed
        __builtin_amdgcn_s_barrier();                        // #0
        for (int t = 1; t < T; ++t) {
            asm volatile("s_waitcnt vmcnt(27)" ::: "memory"); // slot t+1 landed
            __builtin_amdgcn_s_barrier();                     // #t
            int tp = t + 5; if (tp > T - 1) tp = T - 1;
            ISSUE(tp, (t + 5) % 6);
        }
        return;
    }

    // ---------------- compute consumer wave ----------------
    unsigned rbase = ldsU + (unsigned)((r & 31) * 256);
    unsigned gbase = ldsU + 8192u + (unsigned)((r & 31) * 32);

#define SREAD(LL, GA, GB, tt) do {                                           \
        int so_ = ((tt) % 6) * 9216;                                         \
        _Pragma("unroll")                                                    \
        for (int m_ = 0; m_ < 16; ++m_)                                      \
            LL[m_] = ldsr16((int)(rbase + so_ + ((m_ ^ k15) << 4)));         \
        GA = ldsr16((int)(gbase + so_ + ((r & 1) << 4)));                    \
        GB = ldsr16((int)(gbase + so_ + (((r & 1) ^ 1) << 4)));              \
    } while (0)

#define LWAIT() do {                                                         \
        asm volatile("s_waitcnt lgkmcnt(0)" ::: "memory");                   \
        __builtin_amdgcn_sched_barrier(0);                                   \
    } while (0)

#define SCOMP(LL, GA, GB, tt) do {                                           \
        float pl_[8];                                                        \
        _Pragma("unroll")                                                    \
        for (int j_ = 0; j_ < 8; ++j_) pl_[j_] = 0.f;                        \
        _Pragma("unroll")                                                    \
        for (int k_ = 0; k_ < 8; ++k_) {                                     \
            f4v w0_ = LL[2 * k_], w1_ = LL[2 * k_ + 1];                      \
            float ek_ = e[k_];                                               \
            pl_[0] = fmaf(ek_, w0_.x, pl_[0]); pl_[1] = fmaf(ek_, w0_.y, pl_[1]); \
            pl_[2] = fmaf(ek_, w0_.z, pl_[2]); pl_[3] = fmaf(ek_, w0_.w, pl_[3]); \
            pl_[4] = fmaf(ek_, w1_.x, pl_[4]); pl_[5] = fmaf(ek_, w1_.y, pl_[5]); \
            pl_[6] = fmaf(ek_, w1_.z, pl_[6]); pl_[7] = fmaf(ek_, w1_.w, pl_[7]); \
        }                                                                    \
        float gg_[8] = {GA.x, GA.y, GA.z, GA.w, GB.x, GB.y, GB.z, GB.w};     \
        float ss_ = 0.f;                                                     \
        _Pragma("unroll")                                                    \
        for (int j_ = 0; j_ < 8; ++j_) {                                     \
            float a_ = fmaf(pl_[j_], sinv, gg_[j_]);                         \
            e[j_] = __expf(a_);                                              \
            ss_ += e[j_];                                                    \
        }                                                                    \
        sinv = __builtin_amdgcn_rcpf(ss_);                                   \
        if (r < 32) {                                                        \
            f4v v0_ = (f4v){e[0] * sinv, e[1] * sinv, e[2] * sinv, e[3] * sinv}; \
            f4v v1_ = (f4v){e[4] * sinv, e[5] * sinv, e[6] * sinv, e[7] * sinv}; \
            st16(&yp[2 * (tt)], v0_);                                        \
            st16(&yp[2 * (tt) + 1], v1_);                                    \
        }                                                                    \
    } while (0)

    f4v* yp = (f4v*)(yseq + (size_t)b * T * 8);
    float e[8];
    float sinv;

    // ---- t = 0 from initl + gs[0] (plain loads, compiler-tracked) ----
    {
        const f4v* il4 = (const f4v*)(initl + b * 8);
        f4v i0 = il4[0], i1 = il4[1];
        const f4v* g4 = (const f4v*)(gs + b * 8);
        f4v G0 = g4[0], G1 = g4[1];
        float a[8];
        a[0] = fmaf(i0.x, TINV, G0.x); a[1] = fmaf(i0.y, TINV, G0.y);
        a[2] = fmaf(i0.z, TINV, G0.z); a[3] = fmaf(i0.w, TINV, G0.w);
        a[4] = fmaf(i1.x, TINV, G1.x); a[5] = fmaf(i1.y, TINV, G1.y);
        a[6] = fmaf(i1.z, TINV, G1.z); a[7] = fmaf(i1.w, TINV, G1.w);
        float ssum = 0.f;
#pragma unroll
        for (int j = 0; j < 8; ++j) { e[j] = __expf(a[j]); ssum += e[j]; }
        sinv = __builtin_amdgcn_rcpf(ssum);
        if (r < 32) {
            f4v y0v = (f4v){e[0] * sinv, e[1] * sinv, e[2] * sinv, e[3] * sinv};
            f4v y1v = (f4v){e[4] * sinv, e[5] * sinv, e[6] * sinv, e[7] * sinv};
            st16(&yp[0], y0v);
            st16(&yp[1], y1v);
        }
    }

    f4v LA[16], LB[16], gaA, gbA, gaB, gbB;

    __builtin_amdgcn_s_barrier();      // #0: slot 1 landed (producer vmcnt(36))
    SREAD(LA, gaA, gbA, 1);

    for (int t = 1; t < T - 1; t += 2) {
        __builtin_amdgcn_s_barrier();  // #t: slot t+1 landed
        LWAIT();                       // prior phase's SREAD retired
        SREAD(LB, gaB, gbB, t + 1);
        SCOMP(LA, gaA, gbA, t);

        __builtin_amdgcn_s_barrier();  // #t+1: slot t+2 landed
        LWAIT();
        SREAD(LA, gaA, gbA, t + 2);
        SCOMP(LB, gaB, gbB, t + 1);
    }
    __builtin_amdgcn_s_barrier();      // #511
    LWAIT();
    SCOMP(LA, gaA, gbA, T - 1);
#undef ISSUE
#undef SREAD
#undef LWAIT
#undef SCOMP
}

// ---------------- Kernel E: parallel log_q / log_p --------------------------
__global__ __launch_bounds__(256) void lqlp_kernel(
    const float* __restrict__ logits, const float* __restrict__ initl,
    const float* __restrict__ yseq,
    float* __restrict__ logq, float* __restrict__ logp) {
    int tid = blockIdx.x * 256 + threadIdx.x;   // tid = b*T + t
    if (tid >= B * T) return;
    int b = tid >> 9;
    int t = tid & (T - 1);

    const float4* yt4 = (const float4*)(yseq + (size_t)tid * 8);
    float4 y0 = yt4[0], y1 = yt4[1];
    float yt[8] = {y0.x, y0.y, y0.z, y0.w, y1.x, y1.y, y1.z, y1.w};

    float l[8];
    float lp;
    if (t == 0) {
        const float4* il4 = (const float4*)(initl + b * 8);
        float4 i0 = il4[0], i1 = il4[1];
        l[0] = i0.x; l[1] = i0.y; l[2] = i0.z; l[3] = i0.w;
        l[4] = i1.x; l[5] = i1.y; l[6] = i1.z; l[7] = i1.w;
        float sy = ((yt[0] + yt[1]) + (yt[2] + yt[3])) + ((yt[4] + yt[5]) + (yt[6] + yt[7]));
        lp = LOG_INV_K * sy;
    } else {
        const float4* yp4 = (const float4*)(yseq + (size_t)tid * 8 - 8);
        float4 p0 = yp4[0], p1 = yp4[1];
        float ypv[8] = {p0.x, p0.y, p0.z, p0.w, p1.x, p1.y, p1.z, p1.w};
        const float4* L4 = (const float4*)(logits + ((size_t)t * B + b) * 64);
#pragma unroll
        for (int j = 0; j < 8; ++j) l[j] = 0.f;
#pragma unroll
        for (int k = 0; k < 8; ++k) {
            float4 w0 = L4[2 * k], w1 = L4[2 * k + 1];
            float yk = ypv[k];
            l[0] = fmaf(yk, w0.x, l[0]); l[1] = fmaf(yk, w0.y, l[1]);
            l[2] = fmaf(yk, w0.z, l[2]); l[3] = fmaf(yk, w0.w, l[3]);
            l[4] = fmaf(yk, w1.x, l[4]); l[5] = fmaf(yk, w1.y, l[5]);
            l[6] = fmaf(yk, w1.z, l[6]); l[7] = fmaf(yk, w1.w, l[7]);
        }
#pragma unroll
        for (int j = 0; j < 8; ++j) l[j] *= 0.5f;   // stored logits are pre-scaled by 1/tau
        float sy = ((ypv[0] + ypv[1]) + (ypv[2] + ypv[3])) + ((ypv[4] + ypv[5]) + (ypv[6] + ypv[7]));
        float acc = 0.f;
#pragma unroll
        for (int j = 0; j < 8; ++j) {
            float tp = fmaf(DPS, ypv[j], OFFV * sy);
            acc = fmaf(yt[j], logf(fmaxf(tp, 1e-8f)), acc);
        }
        lp = acc;
    }
    float m = fmaxf(fmaxf(fmaxf(l[0], l[1]), fmaxf(l[2], l[3])),
                    fmaxf(fmaxf(l[4], l[5]), fmaxf(l[6], l[7])));
    float se = 0.f;
#pragma unroll
    for (int j = 0; j < 8; ++j) se += __expf(l[j] - m);
    float lse = m + logf(se);
    float lq = 0.f;
#pragma unroll
    for (int j = 0; j < 8; ++j) lq = fmaf(yt[j], l[j] - lse, lq);
    logq[tid] = lq;
    logp[tid] = lp;
}

// ---------------- Kernel F: output einsums, LDS tables + wave roles ---------
// 1024 blocks x 256 thr; block owns 64 bt pairs. Tables (22.5 KB) + y tile
// staged in LDS once. wave0: A (per-lane 8 table f4 in regs); wave1: Q;
// wave2: B (lanes 0-31) + C[0..31] (lanes 32-63, bt-invariant regs);
// wave3: C[32..127]. All stores coalesced f4.
__global__ __launch_bounds__(256) void out_kernel(
    const float* __restrict__ yseq,
    const float* __restrict__ A, const float* __restrict__ Bm,
    const float* __restrict__ C, const float* __restrict__ Q,
    float4* __restrict__ out4) {
    __shared__ float tab[6144];      // A:0..2047  B:2048..3071  Q:3072..5119
                                     // C:5120..5631  Y:5632..6143
    int tid = threadIdx.x;
    int bt0 = blockIdx.x * 64;
    {
        float4* t4 = (float4*)tab;
        const float4* A4 = (const float4*)A;
        const float4* B4 = (const float4*)Bm;
        const float4* Q4 = (const float4*)Q;
        const float4* C4 = (const float4*)C;
        for (int i2 = tid; i2 < 512; i2 += 256) t4[i2] = A4[i2];
        if (tid < 256) t4[512 + tid] = B4[tid];
        for (int i2 = tid; i2 < 512; i2 += 256) t4[768 + i2] = Q4[i2];
        if (tid < 128) t4[1280 + tid] = C4[tid];
        const float4* Y4 = (const float4*)(yseq + (size_t)bt0 * 8);
        if (tid < 128) t4[1408 + tid] = Y4[tid];
    }
    __syncthreads();

    int wave = tid >> 6;
    int lane = tid & 63;
    const float4* t4 = (const float4*)tab;

    if (wave == 0 || wave == 1) {
        // A (wave 0) or Q (wave 1): lane owns output f4 position q = lane.
        int tbase = (wave == 0) ? 0 : 768;
        size_t obase = (wave == 0) ? (size_t)(OUT_A / 4) : (size_t)(OUT_Q / 4);
        float4 wreg[8];
#pragma unroll
        for (int k = 0; k < 8; ++k) wreg[k] = t4[tbase + k * 64 + lane];
        for (int bt = 0; bt < 64; ++bt) {
            float4 ya = t4[1408 + bt * 2];
            float4 yb = t4[1408 + bt * 2 + 1];
            float yk[8] = {ya.x, ya.y, ya.z, ya.w, yb.x, yb.y, yb.z, yb.w};
            float4 v = make_float4(0.f, 0.f, 0.f, 0.f);
#pragma unroll
            for (int k = 0; k < 8; ++k) {
                v.x = fmaf(yk[k], wreg[k].x, v.x);
                v.y = fmaf(yk[k], wreg[k].y, v.y);
                v.z = fmaf(yk[k], wreg[k].z, v.z);
                v.w = fmaf(yk[k], wreg[k].w, v.w);
            }
            out4[obase + (size_t)(bt0 + bt) * 64 + lane] = v;
        }
    } else if (wave == 2) {
        if (lane < 32) {
            float4 wreg[8];
#pragma unroll
            for (int k = 0; k < 8; ++k) wreg[k] = t4[512 + k * 32 + lane];
            for (int bt = 0; bt < 64; ++bt) {
                float4 ya = t4[1408 + bt * 2];
                float4 yb = t4[1408 + bt * 2 + 1];
                float yk[8] = {ya.x, ya.y, ya.z, ya.w, yb.x, yb.y, yb.z, yb.w};
                float4 v = make_float4(0.f, 0.f, 0.f, 0.f);
#pragma unroll
                for (int k = 0; k < 8; ++k) {
                    v.x = fmaf(yk[k], wreg[k].x, v.x);
                    v.y = fmaf(yk[k], wreg[k].y, v.y);
                    v.z = fmaf(yk[k], wreg[k].z, v.z);
                    v.w = fmaf(yk[k], wreg[k].w, v.w);
                }
                out4[(size_t)(OUT_B / 4) + (size_t)(bt0 + bt) * 32 + lane] = v;
            }
        } else {
            float4 c0 = t4[1280 + (lane - 32)];
            for (int bt = 0; bt < 64; ++bt)
                out4[(size_t)(OUT_C / 4) + (size_t)(bt0 + bt) * 128 + (lane - 32)] = c0;
        }
    } else {
        float4 c1 = t4[1280 + 32 + lane];
        float4 c2 = (lane < 32) ? t4[1280 + 96 + lane] : make_float4(0.f, 0.f, 0.f, 0.f);
        for (int bt = 0; bt < 64; ++bt) {
            out4[(size_t)(OUT_C / 4) + (size_t)(bt0 + bt) * 128 + 32 + lane] = c1;
            if (lane < 32)
                out4[(size_t)(OUT_C / 4) + (size_t)(bt0 + bt) * 128 + 96 + lane] = c2;
        }
    }
}

extern "C" void kernel_launch(void* const* d_in, const int* in_sizes, int n_in,
                              void* d_out, int out_size, void* d_ws, size_t ws_size,
                              hipStream_t stream) {
    const float* a_seq = (const float*)d_in[0];
    const float* A     = (const float*)d_in[1];
    const float* Bmat  = (const float*)d_in[2];
    const float* C     = (const float*)d_in[3];
    const float* Q     = (const float*)d_in[4];
    const float* wih_f = (const float*)d_in[5];
    const float* whh_f = (const float*)d_in[6];
    const float* bih_f = (const float*)d_in[7];
    const float* bhh_f = (const float*)d_in[8];
    const float* wih_b = (const float*)d_in[9];
    const float* whh_b = (const float*)d_in[10];
    const float* bih_b = (const float*)d_in[11];
    const float* bhh_b = (const float*)d_in[12];
    const float* wl    = (const float*)d_in[13];
    const float* bl    = (const float*)d_in[14];
    const float* wi    = (const float*)d_in[15];
    const float* bi    = (const float*)d_in[16];
    const float* u0    = (const float*)d_in[17];
    const float* useq  = (const float*)d_in[18];

    float* ws = (float*)d_ws;
    float* gx     = ws + WS_GX;
    float* gsb    = ws + WS_GS;       // aliases gx dir=1 half (written after GRU)
    float* hseq   = ws + WS_HSEQ;
    float* logits = ws + WS_LOGITS;   // aliases gx dir=0 half (written after GRU)
    float* initl  = ws + WS_INIT;
    float* yseq   = ws + WS_YSEQ;

    float* outf = (float*)d_out;
    float* logq = outf + OUT_LQ;
    float* logp = outf + OUT_LP;

    gx_kernel<<<B * (T / 64), 192, 0, stream>>>(a_seq, wih_f, bih_f, wih_b, bih_b, gx);
    gru_kernel<<<256, 64, 0, stream>>>(gx, whh_f, bhh_f, whh_b, bhh_b, hseq);
    {
        int total = B * T * KK;
        gsc_kernel<<<(total + 255) / 256, 256, 0, stream>>>(u0, useq, gsb);
    }
    logits_kernel<<<T * B / 4, 256, 0, stream>>>(hseq, wl, bl, wi, bi, logits, initl);
    scan_kernel<<<4, 128, 0, stream>>>(logits, initl, gsb, yseq);
    lqlp_kernel<<<(B * T + 255) / 256, 256, 0, stream>>>(logits, initl, yseq, logq, logp);
    out_kernel<<<B * T / 64, 256, 0, stream>>>(yseq, A, Bmat, C, Q, (float4*)d_out);
}

// Round 13
// 485.859 us; speedup vs baseline: 1.4638x; 1.1742x over previous
//
#include <hip/hip_runtime.h>
#include <math.h>

#define T 512
#define B 128
#define KK 8
#define HH 32
#define PP 32

// ws layout (floats)
#define WS_GX    0             /* gx [dir*B+b][t][96] = 12582912 floats */
#define WS_GS    6291456       /* alias gx dir=1 half: gumbel noise [t][b][8], written after GRU */
#define WS_HSEQ  12582912
#define WS_LOGITS 0            /* alias gx dir=0 half: scaled logits [t][b][64], written after GRU */
#define WS_INIT  16777216
#define WS_YSEQ  16778240

// d_out layout (floats)
#define OUT_A    0
#define OUT_B    16777216
#define OUT_C    25165824
#define OUT_Q    58720256
#define OUT_LQ   75497472
#define OUT_LP   75563008

#define TINV 2.0f
#define PSTAY 0.9f
#define OFFV (0.1f / 7.0f)
#define DPS (PSTAY - OFFV)
#define LOG_INV_K (-2.0794415416798357f)

typedef float f4v __attribute__((ext_vector_type(4)));
typedef __attribute__((address_space(3))) float as3f;

// async DMA global->LDS, 16B/lane, opaque to compiler (no auto waitcnt insertion)
__device__ __forceinline__ void dma16(unsigned ldsbyte, int voffbyte, const void* sbase) {
    asm volatile("s_mov_b32 m0, %0\n\t"
                 "global_load_lds_dwordx4 %1, %2"
                 :: "s"(ldsbyte), "v"(voffbyte), "s"(sbase)
                 : "memory");
}
// stores kept in asm: compiler does not track them -> no per-iter vmcnt drains
__device__ __forceinline__ void st16(void* p, f4v v) {
    asm volatile("global_store_dwordx4 %0, %1, off" :: "v"(p), "v"(v) : "memory");
}
// pinned LDS read: output lives in registers, cannot be rematerialized at use
__device__ __forceinline__ f4v ldsr16(int addr) {
    f4v out;
    asm volatile("ds_read_b128 %0, %1" : "=v"(out) : "v"(addr));
    return out;
}
// pinned global loads: outputs live in registers; caller does counted vmcnt
__device__ __forceinline__ f4v ldg16(const void* p) {
    f4v out;
    asm volatile("global_load_dwordx4 %0, %1, off" : "=v"(out) : "v"(p) : "memory");
    return out;
}
__device__ __forceinline__ float ldg4(const void* p) {
    float out;
    asm volatile("global_load_dword %0, %1, off" : "=v"(out) : "v"(p) : "memory");
    return out;
}

// ---------------- Kernel A: gx tiled: W in regs, x tile in LDS --------------
__global__ __launch_bounds__(192) void gx_kernel(
    const float* __restrict__ a_seq,
    const float* __restrict__ wih_f, const float* __restrict__ bih_f,
    const float* __restrict__ wih_b, const float* __restrict__ bih_b,
    float* __restrict__ gx) {
    __shared__ float xt[64 * 32];
    int blk = blockIdx.x;
    int b = blk >> 3;
    int t0 = (blk & 7) << 6;
    int g = threadIdx.x;            // 0..191
    int dir = (g >= 96) ? 1 : 0;
    int gg = dir ? (g - 96) : g;
    const float* w = dir ? wih_b : wih_f;
    const float* bv = dir ? bih_b : bih_f;

    {
        const float4* src = (const float4*)(a_seq + ((size_t)b * T + t0) * PP);
        float4* dst = (float4*)xt;
        for (int idx = g; idx < 512; idx += 192) dst[idx] = src[idx];
    }
    float wreg[32];
#pragma unroll
    for (int q = 0; q < 8; ++q) {
        float4 wv = *(const float4*)(w + (size_t)gg * PP + q * 4);
        wreg[q * 4 + 0] = wv.x; wreg[q * 4 + 1] = wv.y;
        wreg[q * 4 + 2] = wv.z; wreg[q * 4 + 3] = wv.w;
    }
    float bias = bv[gg];
    __syncthreads();

    float* op = gx + ((size_t)(dir * B + b) * T + t0) * 96 + gg;
#pragma unroll 4
    for (int r = 0; r < 64; ++r) {
        const float4* xr = (const float4*)(xt + r * 32);
        float acc = bias;
#pragma unroll
        for (int q = 0; q < 8; ++q) {
            float4 xv = xr[q];
            acc = fmaf(xv.x, wreg[q * 4 + 0], acc);
            acc = fmaf(xv.y, wreg[q * 4 + 1], acc);
            acc = fmaf(xv.z, wreg[q * 4 + 2], acc);
            acc = fmaf(xv.w, wreg[q * 4 + 3], acc);
        }
        op[(size_t)r * 96] = acc;
    }
}

// ---------------- Kernel B: GRU scan, all-asm VM ops, counted vmcnt ---------
__global__ __launch_bounds__(64, 1) void gru_kernel(
    const float* __restrict__ gx,
    const float* __restrict__ whh_f, const float* __restrict__ bhh_f,
    const float* __restrict__ whh_b, const float* __restrict__ bhh_b,
    float* __restrict__ hseq) {
    int cid = blockIdx.x;            // 0..255 = dir*128 + b
    int b = cid & 127;
    int dir = cid >> 7;
    int i = threadIdx.x & 31;
    const float* whh = dir ? whh_b : whh_f;
    const float* bhh = dir ? bhh_b : bhh_f;
    const float* gp0 = gx + (size_t)cid * (T * 96);

    // asm-pinned weights + biases (27 vm loads)
    f4v wr[8], wz[8], wn[8];
#pragma unroll
    for (int q = 0; q < 8; ++q) {
        wr[q] = ldg16(whh + (size_t)i * 32 + q * 4);
        wz[q] = ldg16(whh + (size_t)(32 + i) * 32 + q * 4);
        wn[q] = ldg16(whh + (size_t)(64 + i) * 32 + q * 4);
    }
    float bhr = ldg4(bhh + i);
    float bhz = ldg4(bhh + 32 + i);
    float bhn = ldg4(bhh + 64 + i);

    const float* p = gp0 + (dir ? (T - 1) * 96 : 0);
    int gstep = dir ? -96 : 96;
    int voff = (((dir ? (T - 1) : 0) * B + b) * 64 + dir * 32 + i) * 4;
    int vstep = dir ? -(B * 64 * 4) : (B * 64 * 4);

    float pxrA[8], pxzA[8], pxnA[8], pxrB[8], pxzB[8], pxnB[8];

#define LOADG(PR, PZ, PN, G0) do {                                             \
        _Pragma("unroll")                                                      \
        for (int u_ = 0; u_ < 8; ++u_) {                                       \
            int sc_ = (G0) * 8 + u_; if (sc_ > T - 1) sc_ = T - 1;             \
            const float* rp_ = p + sc_ * gstep;                                \
            PR[u_] = ldg4(rp_ + i);                                            \
            PZ[u_] = ldg4(rp_ + 32 + i);                                       \
            PN[u_] = ldg4(rp_ + 64 + i);                                       \
        }                                                                      \
    } while (0)

#define GWAIT(N) do {                                                          \
        asm volatile("s_waitcnt vmcnt(" #N ")" ::: "memory");                  \
        __builtin_amdgcn_sched_barrier(0);                                     \
    } while (0)

#define GSTEP(PR, PZ, PN, SLOT) do {                                           \
        float hr_ = PR[SLOT] + bhr;                                            \
        float hz_ = PZ[SLOT] + bhz;                                            \
        float hn_ = bhn;                                                       \
        _Pragma("unroll")                                                      \
        for (int q_ = 0; q_ < 8; ++q_) {                                       \
            _Pragma("unroll")                                                  \
            for (int c_ = 0; c_ < 4; ++c_) {                                   \
                float hj_ = __uint_as_float(                                   \
                    __builtin_amdgcn_readlane(__float_as_uint(h), q_ * 4 + c_)); \
                hr_ = fmaf(wr[q_][c_], hj_, hr_);                              \
                hz_ = fmaf(wz[q_][c_], hj_, hz_);                              \
                hn_ = fmaf(wn[q_][c_], hj_, hn_);                              \
            }                                                                  \
        }                                                                      \
        float r_ = __builtin_amdgcn_rcpf(1.f + __expf(-hr_));                  \
        float z_ = __builtin_amdgcn_rcpf(1.f + __expf(-hz_));                  \
        float na_ = fmaf(r_, hn_, PN[SLOT]);                                   \
        float e2_ = __expf(-2.f * fabsf(na_));                                 \
        float n_ = copysignf((1.f - e2_) * __builtin_amdgcn_rcpf(1.f + e2_), na_); \
        h = fmaf(z_, h - n_, n_);                                              \
        asm volatile("global_store_dword %0, %1, %2"                           \
                     :: "v"(voff), "v"(h), "s"(hseq) : "memory");              \
        voff += vstep;                                                         \
    } while (0)

    LOADG(pxrA, pxzA, pxnA, 0);
    GWAIT(0);
    float h = 0.f;

    for (int gq = 0; gq < 32; ++gq) {
        LOADG(pxrB, pxzB, pxnB, 2 * gq + 1);          // prefetch next group
        GWAIT(32);                                     // group A's loads landed
        GSTEP(pxrA, pxzA, pxnA, 0); GSTEP(pxrA, pxzA, pxnA, 1);
        GSTEP(pxrA, pxzA, pxnA, 2); GSTEP(pxrA, pxzA, pxnA, 3);
        GSTEP(pxrA, pxzA, pxnA, 4); GSTEP(pxrA, pxzA, pxnA, 5);
        GSTEP(pxrA, pxzA, pxnA, 6); GSTEP(pxrA, pxzA, pxnA, 7);
        LOADG(pxrA, pxzA, pxnA, 2 * gq + 2);
        GWAIT(32);                                     // group B's loads landed
        GSTEP(pxrB, pxzB, pxnB, 0); GSTEP(pxrB, pxzB, pxnB, 1);
        GSTEP(pxrB, pxzB, pxnB, 2); GSTEP(pxrB, pxzB, pxnB, 3);
        GSTEP(pxrB, pxzB, pxnB, 4); GSTEP(pxrB, pxzB, pxnB, 5);
        GSTEP(pxrB, pxzB, pxnB, 6); GSTEP(pxrB, pxzB, pxnB, 7);
    }
#undef LOADG
#undef GWAIT
#undef GSTEP
}

// ---------------- Kernel C: logits' = (h_seq @ wl^T + bl) * (1/tau) ---------
// ONLY change vs round 11: wl staged in LDS with stride-65 padding (bank =
// (g+c)%32, 2 lanes/bank = free) instead of the 64-line global gather.
__global__ __launch_bounds__(256) void logits_kernel(
    const float* __restrict__ hseq,
    const float* __restrict__ wl, const float* __restrict__ bl,
    const float* __restrict__ wi, const float* __restrict__ bi,
    float* __restrict__ logits, float* __restrict__ initl) {
    __shared__ float wls[64 * 65];
    __shared__ float hrow[4][64];
    int tid = threadIdx.x;
    for (int i2 = tid; i2 < 1024; i2 += 256) {
        float4 v = ((const float4*)wl)[i2];
        int gr = i2 >> 4;
        int cc = (i2 & 15) * 4;
        float* d = &wls[gr * 65 + cc];
        d[0] = v.x; d[1] = v.y; d[2] = v.z; d[3] = v.w;
    }
    int q = tid >> 6;
    int tb = blockIdx.x * 4 + q;   // t*B + b
    int g = tid & 63;
    hrow[q][g] = hseq[(size_t)tb * 64 + g];
    __syncthreads();
    float acc = bl[g];
    const float* wrow = &wls[g * 65];
#pragma unroll
    for (int c = 0; c < 64; ++c) acc = fmaf(wrow[c], hrow[q][c], acc);
    logits[(size_t)tb * 64 + g] = acc * TINV;
    if (tb < B && g < 8) {            // t == 0 blocks, tb == b
        float a2 = bi[g];
        const float* w2 = wi + (size_t)g * 64;
#pragma unroll
        for (int c = 0; c < 64; ++c) a2 = fmaf(w2[c], hrow[q][c], a2);
        initl[tb * 8 + g] = a2;
    }
}

// ---------------- Kernel G: gumbel noise [t][b][8], pre-scaled by 1/tau -----
__global__ __launch_bounds__(256) void gsc_kernel(
    const float* __restrict__ u0, const float* __restrict__ useq,
    float* __restrict__ gs) {
    int id = blockIdx.x * 256 + threadIdx.x;
    if (id >= T * B * KK) return;
    int j = id & 7;
    int b = (id >> 3) & 127;
    int t = id >> 10;
    float u = (t == 0) ? u0[b * 8 + j]
                       : useq[((size_t)b * (T - 1) + (t - 1)) * 8 + j];
    gs[id] = -logf(-logf(u)) * TINV;   // precise logf: u near 1 is ill-conditioned
}

// ---------------- Kernel D: y-only scan, producer/consumer wave split -------
// (byte-identical to round 11 — known-good at 183 us)
__global__ __launch_bounds__(128, 1) void scan_kernel(
    const float* __restrict__ logits, const float* __restrict__ initl,
    const float* __restrict__ gs, float* __restrict__ yseq) {
    __shared__ float lds[6][2304];   // 6 slots x (32*64 logits + 32*8 gs)
    int tid = threadIdx.x;
    int wave = tid >> 6;
    int r = tid & 63;
    int b0 = blockIdx.x * 32;
    int b = b0 + (r & 31);
    int k15 = r & 15;

    unsigned ldsU = (unsigned)(unsigned long long)(as3f*)(&lds[0][0]);

#define ISSUE(tt, sl) do {                                                   \
        unsigned lb_ = ldsU + (unsigned)((sl) * 9216);                       \
        const char* bt_ = (const char*)logits + (size_t)(tt) * 32768;        \
        const char* gt_ = (const char*)gs + (size_t)(tt) * 4096;             \
        dma16(lb_ + 0 * 1024u, lof[0], bt_);                                 \
        dma16(lb_ + 1 * 1024u, lof[1], bt_);                                 \
        dma16(lb_ + 2 * 1024u, lof[2], bt_);                                 \
        dma16(lb_ + 3 * 1024u, lof[3], bt_);                                 \
        dma16(lb_ + 4 * 1024u, lof[4], bt_);                                 \
        dma16(lb_ + 5 * 1024u, lof[5], bt_);                                 \
        dma16(lb_ + 6 * 1024u, lof[6], bt_);                                 \
        dma16(lb_ + 7 * 1024u, lof[7], bt_);                                 \
        dma16(lb_ + 8192u, gof, gt_);                                        \
    } while (0)

    if (wave == 1) {
        // ---------------- DMA producer wave ----------------
        int lof[8];
#pragma unroll
        for (int q = 0; q < 8; ++q) {
            int rr = q * 4 + (r >> 4);         // tile row 0..31
            int cc = r & 15;                   // linear f4v col in LDS
            lof[q] = (((b0 + rr) * 64) + ((cc ^ (rr & 15)) << 2)) << 2;
        }
        int gof;
        {
            int rg = r >> 1;
            int cc = r & 1;
            gof = (((b0 + rg) * 8) + ((cc ^ (rg & 1)) << 2)) << 2;
        }
#pragma unroll
        for (int p = 1; p <= 5; ++p) ISSUE(p, p);
        asm volatile("s_waitcnt vmcnt(36)" ::: "memory");   // slot 1 landed
        __builtin_amdgcn_s_barrier();                        // #0
        for (int t = 1; t < T; ++t) {
            asm volatile("s_waitcnt vmcnt(27)" ::: "memory"); // slot t+1 landed
            __builtin_amdgcn_s_barrier();                     // #t
            int tp = t + 5; if (tp > T - 1) tp = T - 1;
            ISSUE(tp, (t + 5) % 6);
        }
        return;
    }

    // ---------------- compute consumer wave ----------------
    unsigned rbase = ldsU + (unsigned)((r & 31) * 256);
    unsigned gbase = ldsU + 8192u + (unsigned)((r & 31) * 32);

#define SREAD(LL, GA, GB, tt) do {                                           \
        int so_ = ((tt) % 6) * 9216;                                         \
        _Pragma("unroll")                                                    \
        for (int m_ = 0; m_ < 16; ++m_)                                      \
            LL[m_] = ldsr16((int)(rbase + so_ + ((m_ ^ k15) << 4)));         \
        GA = ldsr16((int)(gbase + so_ + ((r & 1) << 4)));                    \
        GB = ldsr16((int)(gbase + so_ + (((r & 1) ^ 1) << 4)));              \
    } while (0)

#define LWAIT() do {                                                         \
        asm volatile("s_waitcnt lgkmcnt(0)" ::: "memory");                   \
        __builtin_amdgcn_sched_barrier(0);                                   \
    } while (0)

#define SCOMP(LL, GA, GB, tt) do {                                           \
        float pl_[8];                                                        \
        _Pragma("unroll")                                                    \
        for (int j_ = 0; j_ < 8; ++j_) pl_[j_] = 0.f;                        \
        _Pragma("unroll")                                                    \
        for (int k_ = 0; k_ < 8; ++k_) {                                     \
            f4v w0_ = LL[2 * k_], w1_ = LL[2 * k_ + 1];                      \
            float ek_ = e[k_];                                               \
            pl_[0] = fmaf(ek_, w0_.x, pl_[0]); pl_[1] = fmaf(ek_, w0_.y, pl_[1]); \
            pl_[2] = fmaf(ek_, w0_.z, pl_[2]); pl_[3] = fmaf(ek_, w0_.w, pl_[3]); \
            pl_[4] = fmaf(ek_, w1_.x, pl_[4]); pl_[5] = fmaf(ek_, w1_.y, pl_[5]); \
            pl_[6] = fmaf(ek_, w1_.z, pl_[6]); pl_[7] = fmaf(ek_, w1_.w, pl_[7]); \
        }                                                                    \
        float gg_[8] = {GA.x, GA.y, GA.z, GA.w, GB.x, GB.y, GB.z, GB.w};     \
        float ss_ = 0.f;                                                     \
        _Pragma("unroll")                                                    \
        for (int j_ = 0; j_ < 8; ++j_) {                                     \
            float a_ = fmaf(pl_[j_], sinv, gg_[j_]);                         \
            e[j_] = __expf(a_);                                              \
            ss_ += e[j_];                                                    \
        }                                                                    \
        sinv = __builtin_amdgcn_rcpf(ss_);                                   \
        if (r < 32) {                                                        \
            f4v v0_ = (f4v){e[0] * sinv, e[1] * sinv, e[2] * sinv, e[3] * sinv}; \
            f4v v1_ = (f4v){e[4] * sinv, e[5] * sinv, e[6] * sinv, e[7] * sinv}; \
            st16(&yp[2 * (tt)], v0_);                                        \
            st16(&yp[2 * (tt) + 1], v1_);                                    \
        }                                                                    \
    } while (0)

    f4v* yp = (f4v*)(yseq + (size_t)b * T * 8);
    float e[8];
    float sinv;

    // ---- t = 0 from initl + gs[0] (plain loads, compiler-tracked) ----
    {
        const f4v* il4 = (const f4v*)(initl + b * 8);
        f4v i0 = il4[0], i1 = il4[1];
        const f4v* g4 = (const f4v*)(gs + b * 8);
        f4v G0 = g4[0], G1 = g4[1];
        float a[8];
        a[0] = fmaf(i0.x, TINV, G0.x); a[1] = fmaf(i0.y, TINV, G0.y);
        a[2] = fmaf(i0.z, TINV, G0.z); a[3] = fmaf(i0.w, TINV, G0.w);
        a[4] = fmaf(i1.x, TINV, G1.x); a[5] = fmaf(i1.y, TINV, G1.y);
        a[6] = fmaf(i1.z, TINV, G1.z); a[7] = fmaf(i1.w, TINV, G1.w);
        float ssum = 0.f;
#pragma unroll
        for (int j = 0; j < 8; ++j) { e[j] = __expf(a[j]); ssum += e[j]; }
        sinv = __builtin_amdgcn_rcpf(ssum);
        if (r < 32) {
            f4v y0v = (f4v){e[0] * sinv, e[1] * sinv, e[2] * sinv, e[3] * sinv};
            f4v y1v = (f4v){e[4] * sinv, e[5] * sinv, e[6] * sinv, e[7] * sinv};
            st16(&yp[0], y0v);
            st16(&yp[1], y1v);
        }
    }

    f4v LA[16], LB[16], gaA, gbA, gaB, gbB;

    __builtin_amdgcn_s_barrier();      // #0: slot 1 landed (producer vmcnt(36))
    SREAD(LA, gaA, gbA, 1);

    for (int t = 1; t < T - 1; t += 2) {
        __builtin_amdgcn_s_barrier();  // #t: slot t+1 landed
        LWAIT();                       // prior phase's SREAD retired
        SREAD(LB, gaB, gbB, t + 1);
        SCOMP(LA, gaA, gbA, t);

        __builtin_amdgcn_s_barrier();  // #t+1: slot t+2 landed
        LWAIT();
        SREAD(LA, gaA, gbA, t + 2);
        SCOMP(LB, gaB, gbB, t + 1);
    }
    __builtin_amdgcn_s_barrier();      // #511
    LWAIT();
    SCOMP(LA, gaA, gbA, T - 1);
#undef ISSUE
#undef SREAD
#undef LWAIT
#undef SCOMP
}

// ---------------- Kernel E: parallel log_q / log_p --------------------------
// (byte-identical to round 11)
__global__ __launch_bounds__(256) void lqlp_kernel(
    const float* __restrict__ logits, const float* __restrict__ initl,
    const float* __restrict__ yseq,
    float* __restrict__ logq, float* __restrict__ logp) {
    int tid = blockIdx.x * 256 + threadIdx.x;   // tid = b*T + t
    if (tid >= B * T) return;
    int b = tid >> 9;
    int t = tid & (T - 1);

    const float4* yt4 = (const float4*)(yseq + (size_t)tid * 8);
    float4 y0 = yt4[0], y1 = yt4[1];
    float yt[8] = {y0.x, y0.y, y0.z, y0.w, y1.x, y1.y, y1.z, y1.w};

    float l[8];
    float lp;
    if (t == 0) {
        const float4* il4 = (const float4*)(initl + b * 8);
        float4 i0 = il4[0], i1 = il4[1];
        l[0] = i0.x; l[1] = i0.y; l[2] = i0.z; l[3] = i0.w;
        l[4] = i1.x; l[5] = i1.y; l[6] = i1.z; l[7] = i1.w;
        float sy = ((yt[0] + yt[1]) + (yt[2] + yt[3])) + ((yt[4] + yt[5]) + (yt[6] + yt[7]));
        lp = LOG_INV_K * sy;
    } else {
        const float4* yp4 = (const float4*)(yseq + (size_t)tid * 8 - 8);
        float4 p0 = yp4[0], p1 = yp4[1];
        float ypv[8] = {p0.x, p0.y, p0.z, p0.w, p1.x, p1.y, p1.z, p1.w};
        const float4* L4 = (const float4*)(logits + ((size_t)t * B + b) * 64);
#pragma unroll
        for (int j = 0; j < 8; ++j) l[j] = 0.f;
#pragma unroll
        for (int k = 0; k < 8; ++k) {
            float4 w0 = L4[2 * k], w1 = L4[2 * k + 1];
            float yk = ypv[k];
            l[0] = fmaf(yk, w0.x, l[0]); l[1] = fmaf(yk, w0.y, l[1]);
            l[2] = fmaf(yk, w0.z, l[2]); l[3] = fmaf(yk, w0.w, l[3]);
            l[4] = fmaf(yk, w1.x, l[4]); l[5] = fmaf(yk, w1.y, l[5]);
            l[6] = fmaf(yk, w1.z, l[6]); l[7] = fmaf(yk, w1.w, l[7]);
        }
#pragma unroll
        for (int j = 0; j < 8; ++j) l[j] *= 0.5f;   // stored logits are pre-scaled by 1/tau
        float sy = ((ypv[0] + ypv[1]) + (ypv[2] + ypv[3])) + ((ypv[4] + ypv[5]) + (ypv[6] + ypv[7]));
        float acc = 0.f;
#pragma unroll
        for (int j = 0; j < 8; ++j) {
            float tp = fmaf(DPS, ypv[j], OFFV * sy);
            acc = fmaf(yt[j], logf(fmaxf(tp, 1e-8f)), acc);
        }
        lp = acc;
    }
    float m = fmaxf(fmaxf(fmaxf(l[0], l[1]), fmaxf(l[2], l[3])),
                    fmaxf(fmaxf(l[4], l[5]), fmaxf(l[6], l[7])));
    float se = 0.f;
#pragma unroll
    for (int j = 0; j < 8; ++j) se += __expf(l[j] - m);
    float lse = m + logf(se);
    float lq = 0.f;
#pragma unroll
    for (int j = 0; j < 8; ++j) lq = fmaf(yt[j], l[j] - lse, lq);
    logq[tid] = lq;
    logp[tid] = lp;
}

// ---------------- Kernel F: output einsums, LDS tables + wave roles ---------
__global__ __launch_bounds__(256) void out_kernel(
    const float* __restrict__ yseq,
    const float* __restrict__ A, const float* __restrict__ Bm,
    const float* __restrict__ C, const float* __restrict__ Q,
    float4* __restrict__ out4) {
    __shared__ float tab[6144];      // A:0..2047  B:2048..3071  Q:3072..5119
                                     // C:5120..5631  Y:5632..6143
    int tid = threadIdx.x;
    int bt0 = blockIdx.x * 64;
    {
        float4* t4 = (float4*)tab;
        const float4* A4 = (const float4*)A;
        const float4* B4 = (const float4*)Bm;
        const float4* Q4 = (const float4*)Q;
        const float4* C4 = (const float4*)C;
        for (int i2 = tid; i2 < 512; i2 += 256) t4[i2] = A4[i2];
        if (tid < 256) t4[512 + tid] = B4[tid];
        for (int i2 = tid; i2 < 512; i2 += 256) t4[768 + i2] = Q4[i2];
        if (tid < 128) t4[1280 + tid] = C4[tid];
        const float4* Y4 = (const float4*)(yseq + (size_t)bt0 * 8);
        if (tid < 128) t4[1408 + tid] = Y4[tid];
    }
    __syncthreads();

    int wave = tid >> 6;
    int lane = tid & 63;
    const float4* t4 = (const float4*)tab;

    if (wave == 0 || wave == 1) {
        int tbase = (wave == 0) ? 0 : 768;
        size_t obase = (wave == 0) ? (size_t)(OUT_A / 4) : (size_t)(OUT_Q / 4);
        float4 wreg[8];
#pragma unroll
        for (int k = 0; k < 8; ++k) wreg[k] = t4[tbase + k * 64 + lane];
        for (int bt = 0; bt < 64; ++bt) {
            float4 ya = t4[1408 + bt * 2];
            float4 yb = t4[1408 + bt * 2 + 1];
            float yk[8] = {ya.x, ya.y, ya.z, ya.w, yb.x, yb.y, yb.z, yb.w};
            float4 v = make_float4(0.f, 0.f, 0.f, 0.f);
#pragma unroll
            for (int k = 0; k < 8; ++k) {
                v.x = fmaf(yk[k], wreg[k].x, v.x);
                v.y = fmaf(yk[k], wreg[k].y, v.y);
                v.z = fmaf(yk[k], wreg[k].z, v.z);
                v.w = fmaf(yk[k], wreg[k].w, v.w);
            }
            out4[obase + (size_t)(bt0 + bt) * 64 + lane] = v;
        }
    } else if (wave == 2) {
        if (lane < 32) {
            float4 wreg[8];
#pragma unroll
            for (int k = 0; k < 8; ++k) wreg[k] = t4[512 + k * 32 + lane];
            for (int bt = 0; bt < 64; ++bt) {
                float4 ya = t4[1408 + bt * 2];
                float4 yb = t4[1408 + bt * 2 + 1];
                float yk[8] = {ya.x, ya.y, ya.z, ya.w, yb.x, yb.y, yb.z, yb.w};
                float4 v = make_float4(0.f, 0.f, 0.f, 0.f);
#pragma unroll
                for (int k = 0; k < 8; ++k) {
                    v.x = fmaf(yk[k], wreg[k].x, v.x);
                    v.y = fmaf(yk[k], wreg[k].y, v.y);
                    v.z = fmaf(yk[k], wreg[k].z, v.z);
                    v.w = fmaf(yk[k], wreg[k].w, v.w);
                }
                out4[(size_t)(OUT_B / 4) + (size_t)(bt0 + bt) * 32 + lane] = v;
            }
        } else {
            float4 c0 = t4[1280 + (lane - 32)];
            for (int bt = 0; bt < 64; ++bt)
                out4[(size_t)(OUT_C / 4) + (size_t)(bt0 + bt) * 128 + (lane - 32)] = c0;
        }
    } else {
        float4 c1 = t4[1280 + 32 + lane];
        float4 c2 = (lane < 32) ? t4[1280 + 96 + lane] : make_float4(0.f, 0.f, 0.f, 0.f);
        for (int bt = 0; bt < 64; ++bt) {
            out4[(size_t)(OUT_C / 4) + (size_t)(bt0 + bt) * 128 + 32 + lane] = c1;
            if (lane < 32)
                out4[(size_t)(OUT_C / 4) + (size_t)(bt0 + bt) * 128 + 96 + lane] = c2;
        }
    }
}

extern "C" void kernel_launch(void* const* d_in, const int* in_sizes, int n_in,
                              void* d_out, int out_size, void* d_ws, size_t ws_size,
                              hipStream_t stream) {
    const float* a_seq = (const float*)d_in[0];
    const float* A     = (const float*)d_in[1];
    const float* Bmat  = (const float*)d_in[2];
    const float* C     = (const float*)d_in[3];
    const float* Q     = (const float*)d_in[4];
    const float* wih_f = (const float*)d_in[5];
    const float* whh_f = (const float*)d_in[6];
    const float* bih_f = (const float*)d_in[7];
    const float* bhh_f = (const float*)d_in[8];
    const float* wih_b = (const float*)d_in[9];
    const float* whh_b = (const float*)d_in[10];
    const float* bih_b = (const float*)d_in[11];
    const float* bhh_b = (const float*)d_in[12];
    const float* wl    = (const float*)d_in[13];
    const float* bl    = (const float*)d_in[14];
    const float* wi    = (const float*)d_in[15];
    const float* bi    = (const float*)d_in[16];
    const float* u0    = (const float*)d_in[17];
    const float* useq  = (const float*)d_in[18];

    float* ws = (float*)d_ws;
    float* gx     = ws + WS_GX;
    float* gsb    = ws + WS_GS;       // aliases gx dir=1 half (written after GRU)
    float* hseq   = ws + WS_HSEQ;
    float* logits = ws + WS_LOGITS;   // aliases gx dir=0 half (written after GRU)
    float* initl  = ws + WS_INIT;
    float* yseq   = ws + WS_YSEQ;

    float* outf = (float*)d_out;
    float* logq = outf + OUT_LQ;
    float* logp = outf + OUT_LP;

    gx_kernel<<<B * (T / 64), 192, 0, stream>>>(a_seq, wih_f, bih_f, wih_b, bih_b, gx);
    gru_kernel<<<256, 64, 0, stream>>>(gx, whh_f, bhh_f, whh_b, bhh_b, hseq);
    {
        int total = B * T * KK;
        gsc_kernel<<<(total + 255) / 256, 256, 0, stream>>>(u0, useq, gsb);
    }
    logits_kernel<<<T * B / 4, 256, 0, stream>>>(hseq, wl, bl, wi, bi, logits, initl);
    scan_kernel<<<4, 128, 0, stream>>>(logits, initl, gsb, yseq);
    lqlp_kernel<<<(B * T + 255) / 256, 256, 0, stream>>>(logits, initl, yseq, logq, logp);
    out_kernel<<<B * T / 64, 256, 0, stream>>>(yseq, A, Bmat, C, Q, (float4*)d_out);
}